// Round 1
// baseline (3966.987 us; speedup 1.0000x reference)
//
#include <hip/hip_runtime.h>

#define EMBED 256
#define HEADS 8
#define BATCH 8
#define SEQ   1024
#define NROWS (BATCH * SEQ)                         /* 8192 */
#define QKV_ELEMS ((size_t)HEADS * NROWS * EMBED)   /* 16777216 floats = 64MB */

// ---------------------------------------------------------------------------
// Generic fp32 NT GEMM tile body: C[m][n] = sum_k A[m][k] * Bw[n][k] (+bias[n])
// Block = 256 threads, tile 64x64, BK=16, 4x4 micro-tile per thread.
// ---------------------------------------------------------------------------
__device__ __forceinline__ void gemm_nt_body(
    const float* __restrict__ A, const float* __restrict__ Bw,
    float* __restrict__ C, int N, int K, const float* __restrict__ bias,
    int m0, int n0)
{
    __shared__ float As[16][68];   // [k][m], padded
    __shared__ float Bs[16][68];   // [k][n], padded
    const int tid = threadIdx.x;
    const int ty = tid >> 4, tx = tid & 15;
    const int lr = tid >> 2;           // 0..63 : row within tile
    const int lk = (tid & 3) << 2;     // 0,4,8,12 : k offset (float4)

    float c[4][4];
#pragma unroll
    for (int i = 0; i < 4; ++i)
#pragma unroll
        for (int j = 0; j < 4; ++j) c[i][j] = 0.f;

    for (int k0 = 0; k0 < K; k0 += 16) {
        const float4 av = *(const float4*)(A  + (size_t)(m0 + lr) * K + k0 + lk);
        const float4 bv = *(const float4*)(Bw + (size_t)(n0 + lr) * K + k0 + lk);
        __syncthreads();
        As[lk + 0][lr] = av.x; As[lk + 1][lr] = av.y;
        As[lk + 2][lr] = av.z; As[lk + 3][lr] = av.w;
        Bs[lk + 0][lr] = bv.x; Bs[lk + 1][lr] = bv.y;
        Bs[lk + 2][lr] = bv.z; Bs[lk + 3][lr] = bv.w;
        __syncthreads();
#pragma unroll
        for (int kk = 0; kk < 16; ++kk) {
            const float4 a = *(const float4*)&As[kk][ty << 2];
            const float4 b = *(const float4*)&Bs[kk][tx << 2];
            const float ar[4] = {a.x, a.y, a.z, a.w};
            const float br[4] = {b.x, b.y, b.z, b.w};
#pragma unroll
            for (int i = 0; i < 4; ++i)
#pragma unroll
                for (int j = 0; j < 4; ++j)
                    c[i][j] = fmaf(ar[i], br[j], c[i][j]);
        }
    }

    float4 badd = make_float4(0.f, 0.f, 0.f, 0.f);
    if (bias) badd = *(const float4*)(bias + n0 + (tx << 2));
#pragma unroll
    for (int i = 0; i < 4; ++i) {
        float4 o;
        o.x = c[i][0] + badd.x; o.y = c[i][1] + badd.y;
        o.z = c[i][2] + badd.z; o.w = c[i][3] + badd.w;
        *(float4*)(C + (size_t)(m0 + (ty << 2) + i) * N + n0 + (tx << 2)) = o;
    }
}

// K1: QKV projections. grid = (128, 4, 24); z = op*8 + h, op in {q,k,v}.
__global__ __launch_bounds__(256) void qkv_gemm_kernel(
    const float* __restrict__ X,
    const float* __restrict__ Wq, const float* __restrict__ Wk,
    const float* __restrict__ Wv, float* __restrict__ ws)
{
    const int w  = blockIdx.z;
    const int op = w >> 3;
    const int h  = w & 7;
    const float* Bw = (op == 0 ? Wq : (op == 1 ? Wk : Wv)) + (size_t)h * EMBED * EMBED;
    float* C = ws + (size_t)op * QKV_ELEMS + (size_t)h * NROWS * EMBED;
    gemm_nt_body(X, Bw, C, EMBED, EMBED, nullptr,
                 blockIdx.x * 64, blockIdx.y * 64);
}

// K3: output projection [8192 x 2048] x Wo^T -> [8192 x 256] + bias
__global__ __launch_bounds__(256) void outproj_kernel(
    const float* __restrict__ A, const float* __restrict__ Wo,
    const float* __restrict__ bo, float* __restrict__ out)
{
    gemm_nt_body(A, Wo, out, EMBED, HEADS * EMBED, bo,
                 blockIdx.x * 64, blockIdx.y * 64);
}

// ---------------------------------------------------------------------------
// K2: fp32 causal flash attention.
// grid = (SEQ/32, BATCH, HEADS), block = 256 threads.
// Thread (tr = tid>>3, tc = tid&7): row tr of the 32-query tile, owns output
// dims d = tc + 8*(j&15) + 128*(j>>4) for j in [0,32).
// ---------------------------------------------------------------------------
__global__ __launch_bounds__(256) void flash_kernel(
    const float* __restrict__ qg, const float* __restrict__ kg,
    const float* __restrict__ vg, float* __restrict__ og)
{
    const int qt = blockIdx.x;   // query tile 0..31
    const int b  = blockIdx.y;
    const int h  = blockIdx.z;
    __shared__ float Qs[32][260];
    __shared__ float KVs[32][132];
    __shared__ float Ss[32][33];

    const int tid = threadIdx.x;
    const int tr = tid >> 3, tc = tid & 7;
    const size_t hb = (size_t)(h * BATCH + b) * SEQ * EMBED;
    const int qr0 = qt * 32;

    // load Q tile (32 rows x 256), padded rows (row base 1040B, 16B aligned)
    {
        const float4* src = (const float4*)(qg + hb + (size_t)qr0 * EMBED);
        for (int i = tid; i < 2048; i += 256) {
            const int row = i >> 6, col = i & 63;
            ((float4*)&Qs[row][0])[col] = src[i];
        }
    }

    float acc[32];
#pragma unroll
    for (int i = 0; i < 32; ++i) acc[i] = 0.f;
    float m_r = -__builtin_inff();
    float l_r = 0.f;

    const int nkt = qt + 1;   // causal: key tiles 0..qt
    for (int kt = 0; kt < nkt; ++kt) {
        const float* kbase = kg + hb + (size_t)kt * 32 * EMBED;
        const float* vbase = vg + hb + (size_t)kt * 32 * EMBED;

        // ---- scores S[tr][tc+8u] over two 128-dim halves of K ----
        float s[4] = {0.f, 0.f, 0.f, 0.f};
#pragma unroll
        for (int half = 0; half < 2; ++half) {
            __syncthreads();   // KVs free of previous readers
            for (int i = tid; i < 1024; i += 256) {
                const int row = i >> 5, col = i & 31;
                ((float4*)&KVs[row][0])[col] =
                    ((const float4*)(kbase + (size_t)row * EMBED + half * 128))[col];
            }
            __syncthreads();
            const int dbase = half * 128;
            for (int d = 0; d < 128; ++d) {
                const float qv = Qs[tr][dbase + d];
#pragma unroll
                for (int u = 0; u < 4; ++u)
                    s[u] = fmaf(qv, KVs[tc + (u << 3)][d], s[u]);
            }
        }

        // ---- causal mask + online softmax update ----
        const int qi = qr0 + tr;
#pragma unroll
        for (int u = 0; u < 4; ++u) {
            const int ki = kt * 32 + tc + (u << 3);
            if (ki > qi) s[u] = -__builtin_inff();
        }
        float pm = fmaxf(fmaxf(s[0], s[1]), fmaxf(s[2], s[3]));
#pragma unroll
        for (int off = 1; off < 8; off <<= 1)
            pm = fmaxf(pm, __shfl_xor(pm, off, 8));
        const float m_new = fmaxf(m_r, pm);
        const float sc = __expf(m_r - m_new);   // 0 when m_r == -inf
        float ps = 0.f;
#pragma unroll
        for (int u = 0; u < 4; ++u) { s[u] = __expf(s[u] - m_new); ps += s[u]; }
#pragma unroll
        for (int off = 1; off < 8; off <<= 1)
            ps += __shfl_xor(ps, off, 8);
        l_r = l_r * sc + ps;
        m_r = m_new;
#pragma unroll
        for (int u = 0; u < 4; ++u) Ss[tr][tc + (u << 3)] = s[u];
#pragma unroll
        for (int i = 0; i < 32; ++i) acc[i] *= sc;

        // ---- PV over two 128-dim halves of V (reuses KVs buffer) ----
#pragma unroll
        for (int half = 0; half < 2; ++half) {
            __syncthreads();   // also makes Ss visible on first half
            for (int i = tid; i < 1024; i += 256) {
                const int row = i >> 5, col = i & 31;
                ((float4*)&KVs[row][0])[col] =
                    ((const float4*)(vbase + (size_t)row * EMBED + half * 128))[col];
            }
            __syncthreads();
            const int ibase = half << 4;
            for (int jk = 0; jk < 32; ++jk) {
                const float p = Ss[tr][jk];
#pragma unroll
                for (int i = 0; i < 16; ++i)
                    acc[ibase + i] = fmaf(p, KVs[jk][tc + (i << 3)], acc[ibase + i]);
            }
        }
    }

    // ---- epilogue: o_concat[b][qi][h*256 + d] = acc/l ----
    const float inv = 1.f / l_r;
    float* orow = og + ((size_t)(b * SEQ) + qr0 + tr) * (HEADS * EMBED) + h * EMBED;
#pragma unroll
    for (int i = 0; i < 32; ++i) {
        const int d = tc + ((i & 15) << 3) + ((i >> 4) << 7);
        orow[d] = acc[i] * inv;
    }
}

extern "C" void kernel_launch(void* const* d_in, const int* in_sizes, int n_in,
                              void* d_out, int out_size, void* d_ws, size_t ws_size,
                              hipStream_t stream) {
    const float* X  = (const float*)d_in[0];
    const float* Wq = (const float*)d_in[1];
    const float* Wk = (const float*)d_in[2];
    const float* Wv = (const float*)d_in[3];
    const float* Wo = (const float*)d_in[4];
    const float* bo = (const float*)d_in[5];
    float* ws = (float*)d_ws;
    float* q  = ws;
    float* k  = ws + QKV_ELEMS;
    float* v  = ws + 2 * QKV_ELEMS;
    float* oc = ws + 3 * QKV_ELEMS;   // [B*T][H*EMBED] head-concat, 64MB
    float* out = (float*)d_out;

    dim3 g1(NROWS / 64, EMBED / 64, 24);
    qkv_gemm_kernel<<<g1, 256, 0, stream>>>(X, Wq, Wk, Wv, ws);

    dim3 g2(SEQ / 32, BATCH, HEADS);
    flash_kernel<<<g2, 256, 0, stream>>>(q, k, v, oc);

    dim3 g3(NROWS / 64, EMBED / 64, 1);
    outproj_kernel<<<g3, 256, 0, stream>>>(oc, Wo, bo, out);
}

// Round 2
// 694.814 us; speedup vs baseline: 5.7094x; 5.7094x over previous
//
#include <hip/hip_runtime.h>
#include <hip/hip_bf16.h>

#define EMBED 256
#define HEADS 8
#define BATCH 8
#define SEQ   1024
#define NROWS 8192

typedef __attribute__((ext_vector_type(8))) short short8;   // 8 bf16 (4 VGPR)
typedef __attribute__((ext_vector_type(4))) float f32x4;    // MFMA C/D
typedef unsigned int  uint;
typedef unsigned short ushort;

#define QE   ((size_t)2097152)   /* per-head elems: 8192*256 */

__device__ __forceinline__ ushort f2bf(float f) {
    union { __hip_bfloat16 b; ushort u; } cv; cv.b = __float2bfloat16(f); return cv.u;
}
__device__ __forceinline__ float bf2f(ushort s) {
    union { ushort u; __hip_bfloat16 b; } cv; cv.u = s; return __bfloat162float(cv.b);
}

// ---------------------------------------------------------------------------
// fp32 NT GEMM compute: c[4][4] = A[m0+..][K] x Bw[n0+..][K]^T  (64x64 tile,
// BK=16, 256 threads, 4x4 micro-tile). Epilogue left to caller.
// ---------------------------------------------------------------------------
__device__ __forceinline__ void gemm_nt_compute(
    const float* __restrict__ A, const float* __restrict__ Bw,
    int K, int m0, int n0, float c[4][4])
{
    __shared__ float As[16][68];
    __shared__ float Bs[16][68];
    const int tid = threadIdx.x;
    const int ty = tid >> 4, tx = tid & 15;
    const int lr = tid >> 2;
    const int lk = (tid & 3) << 2;

#pragma unroll
    for (int i = 0; i < 4; ++i)
#pragma unroll
        for (int j = 0; j < 4; ++j) c[i][j] = 0.f;

    for (int k0 = 0; k0 < K; k0 += 16) {
        const float4 av = *(const float4*)(A  + (size_t)(m0 + lr) * K + k0 + lk);
        const float4 bv = *(const float4*)(Bw + (size_t)(n0 + lr) * K + k0 + lk);
        __syncthreads();
        As[lk + 0][lr] = av.x; As[lk + 1][lr] = av.y;
        As[lk + 2][lr] = av.z; As[lk + 3][lr] = av.w;
        Bs[lk + 0][lr] = bv.x; Bs[lk + 1][lr] = bv.y;
        Bs[lk + 2][lr] = bv.z; Bs[lk + 3][lr] = bv.w;
        __syncthreads();
#pragma unroll
        for (int kk = 0; kk < 16; ++kk) {
            const float4 a = *(const float4*)&As[kk][ty << 2];
            const float4 b = *(const float4*)&Bs[kk][tx << 2];
            const float ar[4] = {a.x, a.y, a.z, a.w};
            const float br[4] = {b.x, b.y, b.z, b.w};
#pragma unroll
            for (int i = 0; i < 4; ++i)
#pragma unroll
                for (int j = 0; j < 4; ++j)
                    c[i][j] = fmaf(ar[i], br[j], c[i][j]);
        }
    }
}

// K1a: q/k projections with hi/lo bf16 split. grid=(128,4,16); z = op*8+h.
__global__ __launch_bounds__(256) void qk_proj_kernel(
    const float* __restrict__ X,
    const float* __restrict__ Wq, const float* __restrict__ Wk,
    ushort* __restrict__ qh, ushort* __restrict__ ql,
    ushort* __restrict__ kh, ushort* __restrict__ kl)
{
    const int z = blockIdx.z;
    const int op = z >> 3, h = z & 7;
    const float* Bw = (op == 0 ? Wq : Wk) + (size_t)h * EMBED * EMBED;
    float c[4][4];
    const int m0 = blockIdx.x * 64, n0 = blockIdx.y * 64;
    gemm_nt_compute(X, Bw, EMBED, m0, n0, c);

    ushort* oh = (op == 0 ? qh : kh) + h * QE;
    ushort* ol = (op == 0 ? ql : kl) + h * QE;
    const int ty = threadIdx.x >> 4, tx = threadIdx.x & 15;
#pragma unroll
    for (int i = 0; i < 4; ++i) {
        const size_t off = (size_t)(m0 + (ty << 2) + i) * EMBED + n0 + (tx << 2);
        uint hv[4], lv[4];
#pragma unroll
        for (int j = 0; j < 4; ++j) {
            ushort hb = f2bf(c[i][j]);
            hv[j] = hb;
            lv[j] = f2bf(c[i][j] - bf2f(hb));
        }
        uint2 ph, pl;
        ph.x = hv[0] | (hv[1] << 16); ph.y = hv[2] | (hv[3] << 16);
        pl.x = lv[0] | (lv[1] << 16); pl.y = lv[2] | (lv[3] << 16);
        *(uint2*)(oh + off) = ph;
        *(uint2*)(ol + off) = pl;
    }
}

// K1b: V projection, TRANSPOSED output: VT[h][d][8192] = Wv_h x X^T (bf16).
// grid=(128,4,8): n0 = x*64 over t, m0 = y*64 over d, z = h.
__global__ __launch_bounds__(256) void vt_proj_kernel(
    const float* __restrict__ X, const float* __restrict__ Wv,
    ushort* __restrict__ vt)
{
    const int h = blockIdx.z;
    const float* A = Wv + (size_t)h * EMBED * EMBED;   // [256 d][256 e]
    float c[4][4];
    const int m0 = blockIdx.y * 64, n0 = blockIdx.x * 64;
    // c[i][j] = sum_e Wv_h[m0+..][e] * X[n0+..][e]
    gemm_nt_compute(A, X, EMBED, m0, n0, c);

    ushort* out = vt + (size_t)h * QE;                 // [256][8192]
    const int ty = threadIdx.x >> 4, tx = threadIdx.x & 15;
#pragma unroll
    for (int i = 0; i < 4; ++i) {
        const size_t off = (size_t)(m0 + (ty << 2) + i) * NROWS + n0 + (tx << 2);
        uint2 p;
        p.x = (uint)f2bf(c[i][0]) | ((uint)f2bf(c[i][1]) << 16);
        p.y = (uint)f2bf(c[i][2]) | ((uint)f2bf(c[i][3]) << 16);
        *(uint2*)(out + off) = p;
    }
}

// K3: output projection [8192 x 2048] x Wo^T + bo -> out fp32.
__global__ __launch_bounds__(256) void outproj_kernel(
    const float* __restrict__ A, const float* __restrict__ Wo,
    const float* __restrict__ bo, float* __restrict__ out)
{
    float c[4][4];
    const int m0 = blockIdx.x * 64, n0 = blockIdx.y * 64;
    gemm_nt_compute(A, Wo, HEADS * EMBED, m0, n0, c);
    const int ty = threadIdx.x >> 4, tx = threadIdx.x & 15;
    const float4 badd = *(const float4*)(bo + n0 + (tx << 2));
#pragma unroll
    for (int i = 0; i < 4; ++i) {
        float4 o;
        o.x = c[i][0] + badd.x; o.y = c[i][1] + badd.y;
        o.z = c[i][2] + badd.z; o.w = c[i][3] + badd.w;
        *(float4*)(out + (size_t)(m0 + (ty << 2) + i) * EMBED + n0 + (tx << 2)) = o;
    }
}

// ---------------------------------------------------------------------------
// K2: MFMA flash attention (swapped-operand form).
// grid = 1024 blocks (XCD-swizzled), 256 threads = 4 waves, 64 q-rows/block,
// 16 q-rows/wave, k-tile = 32. S^T = K.Q^T (3-pass hi/lo), O^T = V^T.P^T.
// LDS: Khs/Kls 16KB each (XOR ^(row&7) on 16B blocks), VTs 16KB (phi(d)
// swizzle), Pls 4KB per-wave P bounce. All staged via global_load_lds w=16
// with source-pre-swizzle (dest linear).
// ---------------------------------------------------------------------------
__global__ __launch_bounds__(256) void flash_mfma(
    const ushort* __restrict__ qh, const ushort* __restrict__ ql,
    const ushort* __restrict__ kh, const ushort* __restrict__ kl,
    const ushort* __restrict__ vt, float* __restrict__ oc)
{
    __shared__ ushort Khs[32 * 256];
    __shared__ ushort Kls[32 * 256];
    __shared__ ushort VTs[256 * 32];
    __shared__ ushort Pls[4 * 16 * 32];

    // XCD swizzle: consecutive work-ids (same h,b) land on the same XCD.
    const int bid = blockIdx.x;
    const int wid = (bid & 7) * 128 + (bid >> 3);
    const int qt = wid & 15;
    const int hb = wid >> 4;
    const int h = hb >> 3, b = hb & 7;

    const int tid = threadIdx.x;
    const int w = tid >> 6, l = tid & 63;
    const int g = l >> 4, c16 = l & 15;
    const int qw0 = qt * 64 + w * 16;
    const int q_glob = qw0 + c16;
    const size_t qk_base = (size_t)h * QE + (size_t)b * (SEQ * EMBED);
    const size_t vt_base = (size_t)h * QE + (size_t)b * SEQ;   // + d*8192 + t

    // Q B-fragments, held in registers for the whole block (hi + lo).
    short8 qfh[8], qfl[8];
    {
        const ushort* qr = qh + qk_base + (size_t)q_glob * EMBED + g * 8;
        const ushort* qs = ql + qk_base + (size_t)q_glob * EMBED + g * 8;
#pragma unroll
        for (int kc = 0; kc < 8; ++kc) {
            qfh[kc] = *(const short8*)(qr + kc * 32);
            qfl[kc] = *(const short8*)(qs + kc * 32);
        }
    }

    f32x4 acc[16];
#pragma unroll
    for (int dt = 0; dt < 16; ++dt) acc[dt] = (f32x4){0.f, 0.f, 0.f, 0.f};
    float m_r = -1e30f, l_r = 0.f;

    // staging lane roles
    const int krow_l = l >> 5;      // 0/1: row within 1KB K call
    const int kblk   = l & 31;      // 16B block within 512B row
    const int vd_l   = l >> 2;      // 0..15: d within 1KB VT call
    const int vblk   = l & 3;       // 16B block within 64B row

    const int nkt = 2 * qt + 2;
    for (int kt = 0; kt < nkt; ++kt) {
        __syncthreads();   // all LDS reads of previous iter drained
        // ---- stage K hi/lo (rows 8w..8w+7 per wave, 2 rows per call) ----
#pragma unroll
        for (int j = 0; j < 4; ++j) {
            const int row = 8 * w + 2 * j + krow_l;
            const size_t src = qk_base + (size_t)(kt * 32 + row) * EMBED
                             + ((kblk ^ (row & 7)) * 8);
            __builtin_amdgcn_global_load_lds(kh + src, &Khs[(8 * w + 2 * j) * 256], 16, 0, 0);
            __builtin_amdgcn_global_load_lds(kl + src, &Kls[(8 * w + 2 * j) * 256], 16, 0, 0);
        }
        // ---- stage VT (d rows w*64..w*64+63, 16 rows per call) ----
#pragma unroll
        for (int j = 0; j < 4; ++j) {
            const int d = w * 64 + j * 16 + vd_l;
            const int phi = ((d >> 1) ^ (d >> 3)) & 3;
            const size_t src = vt_base + (size_t)d * NROWS + kt * 32
                             + ((vblk ^ phi) * 8);
            __builtin_amdgcn_global_load_lds(vt + src, &VTs[(w * 64 + j * 16) * 32], 16, 0, 0);
        }
        asm volatile("s_waitcnt vmcnt(0)" ::: "memory");
        __syncthreads();   // staged data visible to all waves

        const bool active = (kt * 32 <= qw0 + 15);
        if (active) {
            // ---- QK^T: S^T[k][q], 3-pass split ----
            f32x4 s0 = (f32x4){0.f, 0.f, 0.f, 0.f};
            f32x4 s1 = (f32x4){0.f, 0.f, 0.f, 0.f};
            const int rsw = c16 & 7;
#pragma unroll
            for (int kc = 0; kc < 8; ++kc) {
                const int blk = ((kc * 4 + g) ^ rsw) * 8;
                short8 a0h = *(const short8*)&Khs[c16 * 256 + blk];
                short8 a0l = *(const short8*)&Kls[c16 * 256 + blk];
                short8 a1h = *(const short8*)&Khs[(c16 + 16) * 256 + blk];
                short8 a1l = *(const short8*)&Kls[(c16 + 16) * 256 + blk];
                s0 = __builtin_amdgcn_mfma_f32_16x16x32_bf16(a0h, qfh[kc], s0, 0, 0, 0);
                s0 = __builtin_amdgcn_mfma_f32_16x16x32_bf16(a0l, qfh[kc], s0, 0, 0, 0);
                s0 = __builtin_amdgcn_mfma_f32_16x16x32_bf16(a0h, qfl[kc], s0, 0, 0, 0);
                s1 = __builtin_amdgcn_mfma_f32_16x16x32_bf16(a1h, qfh[kc], s1, 0, 0, 0);
                s1 = __builtin_amdgcn_mfma_f32_16x16x32_bf16(a1l, qfh[kc], s1, 0, 0, 0);
                s1 = __builtin_amdgcn_mfma_f32_16x16x32_bf16(a1h, qfl[kc], s1, 0, 0, 0);
            }
            // ---- causal mask + online softmax (per-lane row q = c16) ----
            const int k0b = kt * 32 + 4 * g;
            float p0[4], p1[4];
            float pm = -1e30f;
#pragma unroll
            for (int r = 0; r < 4; ++r) {
                p0[r] = (k0b + r      > q_glob) ? -1e30f : s0[r];
                p1[r] = (k0b + 16 + r > q_glob) ? -1e30f : s1[r];
                pm = fmaxf(pm, fmaxf(p0[r], p1[r]));
            }
            pm = fmaxf(pm, __shfl_xor(pm, 16));
            pm = fmaxf(pm, __shfl_xor(pm, 32));
            const float mnew = fmaxf(m_r, pm);
            const float sc = __expf(m_r - mnew);
            float ps = 0.f;
#pragma unroll
            for (int r = 0; r < 4; ++r) {
                p0[r] = __expf(p0[r] - mnew);
                p1[r] = __expf(p1[r] - mnew);
                ps += p0[r] + p1[r];
            }
            ps += __shfl_xor(ps, 16);
            ps += __shfl_xor(ps, 32);
            l_r = l_r * sc + ps;
            m_r = mnew;
#pragma unroll
            for (int dt = 0; dt < 16; ++dt) acc[dt] *= sc;

            // ---- P bounce: C-layout -> B-fragment via per-wave LDS ----
            char* pw = (char*)&Pls[w * 512];
            const int psw = (c16 >> 1) & 3;
#pragma unroll
            for (int t = 0; t < 2; ++t)
#pragma unroll
                for (int u = 0; u < 2; ++u) {
                    const float plo = t ? p1[2 * u] : p0[2 * u];
                    const float phi2 = t ? p1[2 * u + 1] : p0[2 * u + 1];
                    const uint pk = (uint)f2bf(plo) | ((uint)f2bf(phi2) << 16);
                    const int kk = 16 * t + 4 * g + 2 * u;
                    *(uint*)(pw + c16 * 64 + (((kk >> 3) ^ psw) * 16) + (kk & 7) * 2) = pk;
                }
            const short8 pfrag = *(const short8*)(pw + c16 * 64 + ((g ^ psw) * 16));

            // ---- PV: O^T[d][q] += V^T . P^T ----
#pragma unroll
            for (int dt = 0; dt < 16; ++dt) {
                const int d = dt * 16 + c16;
                const int phi = ((d >> 1) ^ (d >> 3)) & 3;
                const short8 va = *(const short8*)&VTs[d * 32 + ((g ^ phi) * 8)];
                acc[dt] = __builtin_amdgcn_mfma_f32_16x16x32_bf16(va, pfrag, acc[dt], 0, 0, 0);
            }
        }
    }

    // ---- epilogue: oc[b][q][h*256 + d] = O^T / l ----
    const float inv = 1.f / l_r;
    float* orow = oc + ((size_t)(b * SEQ) + q_glob) * (HEADS * EMBED) + h * EMBED;
#pragma unroll
    for (int dt = 0; dt < 16; ++dt) {
        f32x4 o = acc[dt] * inv;
        *(f32x4*)(orow + dt * 16 + 4 * g) = o;
    }
}

extern "C" void kernel_launch(void* const* d_in, const int* in_sizes, int n_in,
                              void* d_out, int out_size, void* d_ws, size_t ws_size,
                              hipStream_t stream) {
    const float* X  = (const float*)d_in[0];
    const float* Wq = (const float*)d_in[1];
    const float* Wk = (const float*)d_in[2];
    const float* Wv = (const float*)d_in[3];
    const float* Wo = (const float*)d_in[4];
    const float* bo = (const float*)d_in[5];

    ushort* ws16 = (ushort*)d_ws;
    ushort* qh = ws16;               // 8 heads x 8192 x 256 bf16
    ushort* ql = ws16 + 8 * QE;
    ushort* kh = ws16 + 16 * QE;
    ushort* kl = ws16 + 24 * QE;
    ushort* vt = ws16 + 32 * QE;     // [h][256 d][8192 t] bf16
    float*  oc = (float*)(ws16 + 40 * QE);   // [8192][2048] fp32
    float*  out = (float*)d_out;

    dim3 g1a(NROWS / 64, EMBED / 64, 16);
    qk_proj_kernel<<<g1a, 256, 0, stream>>>(X, Wq, Wk, qh, ql, kh, kl);

    dim3 g1b(NROWS / 64, EMBED / 64, 8);
    vt_proj_kernel<<<g1b, 256, 0, stream>>>(X, Wv, vt);

    flash_mfma<<<dim3(1024), 256, 0, stream>>>(qh, ql, kh, kl, vt, oc);

    dim3 g3(NROWS / 64, EMBED / 64, 1);
    outproj_kernel<<<g3, 256, 0, stream>>>(oc, Wo, bo, out);
}

// Round 4
// 366.694 us; speedup vs baseline: 10.8182x; 1.8948x over previous
//
#include <hip/hip_runtime.h>
#include <hip/hip_bf16.h>

#define EMBED 256
#define HEADS 8
#define BATCH 8
#define SEQ   1024
#define NROWS 8192

typedef __attribute__((ext_vector_type(8))) short short8;   // 8 bf16 (4 VGPR)
typedef __attribute__((ext_vector_type(4))) float f32x4;    // MFMA C/D
typedef unsigned int  uint;
typedef unsigned short ushort;

#define QE   ((size_t)2097152)   /* per-head elems: 8192*256 */

__device__ __forceinline__ ushort f2bf(float f) {
    union { __hip_bfloat16 b; ushort u; } cv; cv.b = __float2bfloat16(f); return cv.u;
}
__device__ __forceinline__ float bf2f(ushort s) {
    union { ushort u; __hip_bfloat16 b; } cv; cv.u = s; return __bfloat162float(cv.b);
}

// ---------------------------------------------------------------------------
// K0: elementwise hi/lo bf16 split (float4-vectorized). n4 = elems/4.
// ---------------------------------------------------------------------------
__global__ __launch_bounds__(256) void split_bf16(
    const float* __restrict__ src, ushort* __restrict__ dh,
    ushort* __restrict__ dl, int n4)
{
    const int i = blockIdx.x * 256 + threadIdx.x;
    if (i >= n4) return;
    const float4 v = ((const float4*)src)[i];
    const float vv[4] = {v.x, v.y, v.z, v.w};
    uint hp[4], lp[4];
#pragma unroll
    for (int j = 0; j < 4; ++j) {
        const ushort hb = f2bf(vv[j]);
        hp[j] = hb;
        lp[j] = f2bf(vv[j] - bf2f(hb));
    }
    uint2 H, L;
    H.x = hp[0] | (hp[1] << 16); H.y = hp[2] | (hp[3] << 16);
    L.x = lp[0] | (lp[1] << 16); L.y = lp[2] | (lp[3] << 16);
    ((uint2*)dh)[i] = H;
    ((uint2*)dl)[i] = L;
}

// ---------------------------------------------------------------------------
// MFMA 3-pass hi/lo GEMM body (NT): C[m][n] = sum_k A[m][k]*B[n][k]
// BM=128, BN in {128,64}, BK=64, 256 threads = 4 waves (2x2), 16x16x32 bf16.
// Staging: global_load_lds w=16, source pre-swizzled ^(row&7) on 16B blocks.
// MODE 0: qk hi/lo split write; MODE 1: vt bf16 write; MODE 2: fp32 out+bias.
// Wrapped by non-template __global__ kernels below (template __global__ +
// extern "C" launch loses the device stub in this .so compile mode).
// ---------------------------------------------------------------------------
template<int BN, int KD, int MODE>
__device__ __forceinline__ void gemm3p_body(
    const ushort* __restrict__ Agh, const ushort* __restrict__ Agl,
    const ushort* __restrict__ Bgh, const ushort* __restrict__ Bgl,
    ushort* __restrict__ o0, ushort* __restrict__ o1,
    ushort* __restrict__ o2, ushort* __restrict__ o3,
    const float* __restrict__ bias, float* __restrict__ fo, int Ntiles)
{
    constexpr int NF = BN / 32;           // n-frags per wave
    __shared__ __align__(16) ushort Ah[128 * 64], Al[128 * 64];
    __shared__ __align__(16) ushort Bh[BN * 64],  Bl[BN * 64];

    const int cpx = gridDim.x >> 3;       // grid divisible by 8
    const int wg  = (blockIdx.x & 7) * cpx + (blockIdx.x >> 3);
    const int m0 = (wg / Ntiles) * 128;
    const int n0 = (wg % Ntiles) * BN;

    const int tid = threadIdx.x, w = tid >> 6, l = tid & 63;
    const int wr = w >> 1, wc = w & 1, g = l >> 4, c16 = l & 15;
    const int sr = l >> 3, sb = l & 7;    // staging: row-in-call, 16B block

    f32x4 acc[4][NF];
#pragma unroll
    for (int mi = 0; mi < 4; ++mi)
#pragma unroll
        for (int ni = 0; ni < NF; ++ni) acc[mi][ni] = (f32x4){0.f, 0.f, 0.f, 0.f};

    for (int k0 = 0; k0 < KD; k0 += 64) {
        __syncthreads();
        // ---- stage A (128 rows x 64 k, hi+lo) ----
#pragma unroll
        for (int j = 0; j < 4; ++j) {
            const int rb = w * 32 + j * 8;
            const int r  = rb + sr;
            const size_t src = (size_t)(m0 + r) * KD + k0 + ((sb ^ (r & 7)) * 8);
            __builtin_amdgcn_global_load_lds(Agh + src, &Ah[rb * 64], 16, 0, 0);
            __builtin_amdgcn_global_load_lds(Agl + src, &Al[rb * 64], 16, 0, 0);
        }
        // ---- stage B (BN rows x 64 k, hi+lo) ----
#pragma unroll
        for (int j = 0; j < BN / 32; ++j) {
            const int rb = w * (BN / 4) + j * 8;
            const int r  = rb + sr;
            const size_t src = (size_t)(n0 + r) * KD + k0 + ((sb ^ (r & 7)) * 8);
            __builtin_amdgcn_global_load_lds(Bgh + src, &Bh[rb * 64], 16, 0, 0);
            __builtin_amdgcn_global_load_lds(Bgl + src, &Bl[rb * 64], 16, 0, 0);
        }
        asm volatile("s_waitcnt vmcnt(0)" ::: "memory");
        __syncthreads();

#pragma unroll
        for (int kh = 0; kh < 2; ++kh) {
            const int bsel = ((kh << 2) | g) ^ (c16 & 7);
            short8 afh[4], afl[4], bfh[NF], bfl[NF];
#pragma unroll
            for (int mi = 0; mi < 4; ++mi) {
                const int row = wr * 64 + mi * 16 + c16;
                afh[mi] = *(const short8*)&Ah[row * 64 + bsel * 8];
                afl[mi] = *(const short8*)&Al[row * 64 + bsel * 8];
            }
#pragma unroll
            for (int ni = 0; ni < NF; ++ni) {
                const int row = wc * (BN / 2) + ni * 16 + c16;
                bfh[ni] = *(const short8*)&Bh[row * 64 + bsel * 8];
                bfl[ni] = *(const short8*)&Bl[row * 64 + bsel * 8];
            }
#pragma unroll
            for (int mi = 0; mi < 4; ++mi)
#pragma unroll
                for (int ni = 0; ni < NF; ++ni) {
                    acc[mi][ni] = __builtin_amdgcn_mfma_f32_16x16x32_bf16(afh[mi], bfh[ni], acc[mi][ni], 0, 0, 0);
                    acc[mi][ni] = __builtin_amdgcn_mfma_f32_16x16x32_bf16(afl[mi], bfh[ni], acc[mi][ni], 0, 0, 0);
                    acc[mi][ni] = __builtin_amdgcn_mfma_f32_16x16x32_bf16(afh[mi], bfl[ni], acc[mi][ni], 0, 0, 0);
                }
        }
    }

    // ---- epilogue ----
#pragma unroll
    for (int mi = 0; mi < 4; ++mi)
#pragma unroll
        for (int ni = 0; ni < NF; ++ni) {
            const int n = n0 + wc * (BN / 2) + ni * 16 + c16;
            if constexpr (MODE == 0) {
                const int op = n >> 11, hh = (n >> 8) & 7, d = n & 255;
                ushort* th = (op ? o2 : o0) + (size_t)hh * QE + d;
                ushort* tl = (op ? o3 : o1) + (size_t)hh * QE + d;
#pragma unroll
                for (int j = 0; j < 4; ++j) {
                    const int m = m0 + wr * 64 + mi * 16 + 4 * g + j;
                    const float v = acc[mi][ni][j];
                    const ushort hb = f2bf(v);
                    th[(size_t)m * 256] = hb;
                    tl[(size_t)m * 256] = f2bf(v - bf2f(hb));
                }
            } else if constexpr (MODE == 1) {
#pragma unroll
                for (int j = 0; j < 4; ++j) {
                    const int m = m0 + wr * 64 + mi * 16 + 4 * g + j;
                    o0[(size_t)m * NROWS + n] = f2bf(acc[mi][ni][j]);
                }
            } else {
                const float bb = bias[n];
#pragma unroll
                for (int j = 0; j < 4; ++j) {
                    const int m = m0 + wr * 64 + mi * 16 + 4 * g + j;
                    fo[(size_t)m * 256 + n] = acc[mi][ni][j] + bb;
                }
            }
        }
}

// Non-template wrappers (stubs emit correctly for extern "C" launch).
__global__ __launch_bounds__(256) void gemm_qk(
    const ushort* __restrict__ Agh, const ushort* __restrict__ Agl,
    const ushort* __restrict__ Bgh, const ushort* __restrict__ Bgl,
    ushort* __restrict__ qh, ushort* __restrict__ ql,
    ushort* __restrict__ kh, ushort* __restrict__ kl)
{
    gemm3p_body<128, 256, 0>(Agh, Agl, Bgh, Bgl, qh, ql, kh, kl, nullptr, nullptr, 32);
}

__global__ __launch_bounds__(256) void gemm_vt(
    const ushort* __restrict__ Agh, const ushort* __restrict__ Agl,
    const ushort* __restrict__ Bgh, const ushort* __restrict__ Bgl,
    ushort* __restrict__ vt)
{
    gemm3p_body<128, 256, 1>(Agh, Agl, Bgh, Bgl, vt, nullptr, nullptr, nullptr, nullptr, nullptr, 64);
}

__global__ __launch_bounds__(256) void gemm_out(
    const ushort* __restrict__ Agh, const ushort* __restrict__ Agl,
    const ushort* __restrict__ Bgh, const ushort* __restrict__ Bgl,
    const float* __restrict__ bias, float* __restrict__ fo)
{
    gemm3p_body<64, 2048, 2>(Agh, Agl, Bgh, Bgl, nullptr, nullptr, nullptr, nullptr, bias, fo, 4);
}

// ---------------------------------------------------------------------------
// K2: MFMA flash attention (swapped-operand form). Epilogue emits och/ocl
// bf16 hi/lo pairs for the MFMA output projection.
// ---------------------------------------------------------------------------
__global__ __launch_bounds__(256) void flash_mfma(
    const ushort* __restrict__ qh, const ushort* __restrict__ ql,
    const ushort* __restrict__ kh, const ushort* __restrict__ kl,
    const ushort* __restrict__ vt,
    ushort* __restrict__ och, ushort* __restrict__ ocl)
{
    __shared__ __align__(16) ushort Khs[32 * 256];
    __shared__ __align__(16) ushort Kls[32 * 256];
    __shared__ __align__(16) ushort VTs[256 * 32];
    __shared__ __align__(16) ushort Pls[4 * 16 * 32];

    const int bid = blockIdx.x;
    const int wid = (bid & 7) * 128 + (bid >> 3);
    const int qt = wid & 15;
    const int hb = wid >> 4;
    const int h = hb >> 3, b = hb & 7;

    const int tid = threadIdx.x;
    const int w = tid >> 6, l = tid & 63;
    const int g = l >> 4, c16 = l & 15;
    const int qw0 = qt * 64 + w * 16;
    const int q_glob = qw0 + c16;
    const size_t qk_base = (size_t)h * QE + (size_t)b * (SEQ * EMBED);
    const size_t vt_base = (size_t)h * QE + (size_t)b * SEQ;

    short8 qfh[8], qfl[8];
    {
        const ushort* qr = qh + qk_base + (size_t)q_glob * EMBED + g * 8;
        const ushort* qs = ql + qk_base + (size_t)q_glob * EMBED + g * 8;
#pragma unroll
        for (int kc = 0; kc < 8; ++kc) {
            qfh[kc] = *(const short8*)(qr + kc * 32);
            qfl[kc] = *(const short8*)(qs + kc * 32);
        }
    }

    f32x4 acc[16];
#pragma unroll
    for (int dt = 0; dt < 16; ++dt) acc[dt] = (f32x4){0.f, 0.f, 0.f, 0.f};
    float m_r = -1e30f, l_r = 0.f;

    const int krow_l = l >> 5;
    const int kblk   = l & 31;
    const int vd_l   = l >> 2;
    const int vblk   = l & 3;

    const int nkt = 2 * qt + 2;
    for (int kt = 0; kt < nkt; ++kt) {
        __syncthreads();
#pragma unroll
        for (int j = 0; j < 4; ++j) {
            const int row = 8 * w + 2 * j + krow_l;
            const size_t src = qk_base + (size_t)(kt * 32 + row) * EMBED
                             + ((kblk ^ (row & 7)) * 8);
            __builtin_amdgcn_global_load_lds(kh + src, &Khs[(8 * w + 2 * j) * 256], 16, 0, 0);
            __builtin_amdgcn_global_load_lds(kl + src, &Kls[(8 * w + 2 * j) * 256], 16, 0, 0);
        }
#pragma unroll
        for (int j = 0; j < 4; ++j) {
            const int d = w * 64 + j * 16 + vd_l;
            const int phi = ((d >> 1) ^ (d >> 3)) & 3;
            const size_t src = vt_base + (size_t)d * NROWS + kt * 32
                             + ((vblk ^ phi) * 8);
            __builtin_amdgcn_global_load_lds(vt + src, &VTs[(w * 64 + j * 16) * 32], 16, 0, 0);
        }
        asm volatile("s_waitcnt vmcnt(0)" ::: "memory");
        __syncthreads();

        const bool active = (kt * 32 <= qw0 + 15);
        if (active) {
            f32x4 s0 = (f32x4){0.f, 0.f, 0.f, 0.f};
            f32x4 s1 = (f32x4){0.f, 0.f, 0.f, 0.f};
            const int rsw = c16 & 7;
#pragma unroll
            for (int kc = 0; kc < 8; ++kc) {
                const int blk = ((kc * 4 + g) ^ rsw) * 8;
                short8 a0h = *(const short8*)&Khs[c16 * 256 + blk];
                short8 a0l = *(const short8*)&Kls[c16 * 256 + blk];
                short8 a1h = *(const short8*)&Khs[(c16 + 16) * 256 + blk];
                short8 a1l = *(const short8*)&Kls[(c16 + 16) * 256 + blk];
                s0 = __builtin_amdgcn_mfma_f32_16x16x32_bf16(a0h, qfh[kc], s0, 0, 0, 0);
                s0 = __builtin_amdgcn_mfma_f32_16x16x32_bf16(a0l, qfh[kc], s0, 0, 0, 0);
                s0 = __builtin_amdgcn_mfma_f32_16x16x32_bf16(a0h, qfl[kc], s0, 0, 0, 0);
                s1 = __builtin_amdgcn_mfma_f32_16x16x32_bf16(a1h, qfh[kc], s1, 0, 0, 0);
                s1 = __builtin_amdgcn_mfma_f32_16x16x32_bf16(a1l, qfh[kc], s1, 0, 0, 0);
                s1 = __builtin_amdgcn_mfma_f32_16x16x32_bf16(a1h, qfl[kc], s1, 0, 0, 0);
            }
            const int k0b = kt * 32 + 4 * g;
            float p0[4], p1[4];
            float pm = -1e30f;
#pragma unroll
            for (int r = 0; r < 4; ++r) {
                p0[r] = (k0b + r      > q_glob) ? -1e30f : s0[r];
                p1[r] = (k0b + 16 + r > q_glob) ? -1e30f : s1[r];
                pm = fmaxf(pm, fmaxf(p0[r], p1[r]));
            }
            pm = fmaxf(pm, __shfl_xor(pm, 16));
            pm = fmaxf(pm, __shfl_xor(pm, 32));
            const float mnew = fmaxf(m_r, pm);
            const float sc = __expf(m_r - mnew);
            float ps = 0.f;
#pragma unroll
            for (int r = 0; r < 4; ++r) {
                p0[r] = __expf(p0[r] - mnew);
                p1[r] = __expf(p1[r] - mnew);
                ps += p0[r] + p1[r];
            }
            ps += __shfl_xor(ps, 16);
            ps += __shfl_xor(ps, 32);
            l_r = l_r * sc + ps;
            m_r = mnew;
#pragma unroll
            for (int dt = 0; dt < 16; ++dt) acc[dt] *= sc;

            char* pw = (char*)&Pls[w * 512];
            const int psw = (c16 >> 1) & 3;
#pragma unroll
            for (int t = 0; t < 2; ++t)
#pragma unroll
                for (int u = 0; u < 2; ++u) {
                    const float plo = t ? p1[2 * u] : p0[2 * u];
                    const float phi2 = t ? p1[2 * u + 1] : p0[2 * u + 1];
                    const uint pk = (uint)f2bf(plo) | ((uint)f2bf(phi2) << 16);
                    const int kk = 16 * t + 4 * g + 2 * u;
                    *(uint*)(pw + c16 * 64 + (((kk >> 3) ^ psw) * 16) + (kk & 7) * 2) = pk;
                }
            const short8 pfrag = *(const short8*)(pw + c16 * 64 + ((g ^ psw) * 16));

#pragma unroll
            for (int dt = 0; dt < 16; ++dt) {
                const int d = dt * 16 + c16;
                const int phi = ((d >> 1) ^ (d >> 3)) & 3;
                const short8 va = *(const short8*)&VTs[d * 32 + ((g ^ phi) * 8)];
                acc[dt] = __builtin_amdgcn_mfma_f32_16x16x32_bf16(va, pfrag, acc[dt], 0, 0, 0);
            }
        }
    }

    // ---- epilogue: och/ocl[b*SEQ+q][h*256+d] bf16 hi/lo ----
    const float inv = 1.f / l_r;
    const size_t obase = ((size_t)(b * SEQ) + q_glob) * (HEADS * EMBED) + h * EMBED;
#pragma unroll
    for (int dt = 0; dt < 16; ++dt) {
        const f32x4 o = acc[dt] * inv;
        uint hp[4], lp[4];
#pragma unroll
        for (int j = 0; j < 4; ++j) {
            const ushort hb2 = f2bf(o[j]);
            hp[j] = hb2;
            lp[j] = f2bf(o[j] - bf2f(hb2));
        }
        uint2 H, L;
        H.x = hp[0] | (hp[1] << 16); H.y = hp[2] | (hp[3] << 16);
        L.x = lp[0] | (lp[1] << 16); L.y = lp[2] | (lp[3] << 16);
        *(uint2*)(och + obase + dt * 16 + 4 * g) = H;
        *(uint2*)(ocl + obase + dt * 16 + 4 * g) = L;
    }
}

extern "C" void kernel_launch(void* const* d_in, const int* in_sizes, int n_in,
                              void* d_out, int out_size, void* d_ws, size_t ws_size,
                              hipStream_t stream) {
    const float* X  = (const float*)d_in[0];
    const float* Wq = (const float*)d_in[1];
    const float* Wk = (const float*)d_in[2];
    const float* Wv = (const float*)d_in[3];
    const float* Wo = (const float*)d_in[4];
    const float* bo = (const float*)d_in[5];

    ushort* ws16 = (ushort*)d_ws;
    ushort* qh   = ws16;                     // [8][8192][256] bf16
    ushort* ql   = ws16 +  8 * QE;
    ushort* kh   = ws16 + 16 * QE;
    ushort* kl   = ws16 + 24 * QE;
    ushort* vt   = ws16 + 32 * QE;           // [2048][8192] bf16
    ushort* och  = ws16 + 40 * QE;           // [8192][2048] bf16 hi
    ushort* ocl  = ws16 + 48 * QE;           // [8192][2048] bf16 lo
    ushort* ex   = ws16 + 56 * QE;           // extras
    ushort* Xh   = ex;                       // 2M
    ushort* Xl   = ex + 2097152;
    ushort* Wqkh = ex + 2 * 2097152;         // [4096][256] = 1M
    ushort* Wqkl = ex + 3 * 2097152;
    ushort* Wvh  = ex + 4 * 2097152;         // 0.5M
    ushort* Wvl  = ex + 4 * 2097152 + 524288;
    ushort* Woh  = ex + 5 * 2097152;         // [256][2048] = 0.5M
    ushort* Wol  = ex + 5 * 2097152 + 524288;
    float*  out  = (float*)d_out;

    // K0: splits
    split_bf16<<<2048, 256, 0, stream>>>(X,  Xh,   Xl,   524288);
    split_bf16<<<512, 256, 0, stream>>>(Wq, Wqkh, Wqkl, 131072);
    split_bf16<<<512, 256, 0, stream>>>(Wk, Wqkh + 524288, Wqkl + 524288, 131072);
    split_bf16<<<512, 256, 0, stream>>>(Wv, Wvh,  Wvl,  131072);
    split_bf16<<<512, 256, 0, stream>>>(Wo, Woh,  Wol,  131072);

    // GEMM1: [8192x256] x [4096x256]^T -> qh/ql/kh/kl
    gemm_qk<<<2048, 256, 0, stream>>>(Xh, Xl, Wqkh, Wqkl, qh, ql, kh, kl);

    // GEMM2: vt[2048][8192] = Wv x X^T
    gemm_vt<<<1024, 256, 0, stream>>>(Wvh, Wvl, Xh, Xl, vt);

    // K2: flash attention
    flash_mfma<<<1024, 256, 0, stream>>>(qh, ql, kh, kl, vt, och, ocl);

    // GEMM3: out[8192][256] = oc x Wo^T + bo
    gemm_out<<<256, 256, 0, stream>>>(och, ocl, Woh, Wol, bo, out);
}

// Round 5
// 314.136 us; speedup vs baseline: 12.6282x; 1.1673x over previous
//
#include <hip/hip_runtime.h>
#include <hip/hip_bf16.h>

#define EMBED 256
#define HEADS 8
#define BATCH 8
#define SEQ   1024
#define NROWS 8192

typedef __attribute__((ext_vector_type(8))) short short8;   // 8 bf16 (4 VGPR)
typedef __attribute__((ext_vector_type(4))) float f32x4;    // MFMA C/D
typedef unsigned int  uint;
typedef unsigned short ushort;

#define QE   ((size_t)2097152)   /* per-head elems: 8192*256 */

__device__ __forceinline__ ushort f2bf(float f) {
    union { __hip_bfloat16 b; ushort u; } cv; cv.b = __float2bfloat16(f); return cv.u;
}
__device__ __forceinline__ float bf2f(ushort s) {
    union { ushort u; __hip_bfloat16 b; } cv; cv.u = s; return __bfloat162float(cv.b);
}

// ---------------------------------------------------------------------------
// K0a: X hi/lo bf16 split (float4-vectorized). n4 = elems/4.
// ---------------------------------------------------------------------------
__global__ __launch_bounds__(256) void split_bf16(
    const float* __restrict__ src, ushort* __restrict__ dh,
    ushort* __restrict__ dl, int n4)
{
    const int i = blockIdx.x * 256 + threadIdx.x;
    if (i >= n4) return;
    const float4 v = ((const float4*)src)[i];
    const float vv[4] = {v.x, v.y, v.z, v.w};
    uint hp[4], lp[4];
#pragma unroll
    for (int j = 0; j < 4; ++j) {
        const ushort hb = f2bf(vv[j]);
        hp[j] = hb;
        lp[j] = f2bf(vv[j] - bf2f(hb));
    }
    uint2 H, L;
    H.x = hp[0] | (hp[1] << 16); H.y = hp[2] | (hp[3] << 16);
    L.x = lp[0] | (lp[1] << 16); L.y = lp[2] | (lp[3] << 16);
    ((uint2*)dh)[i] = H;
    ((uint2*)dl)[i] = L;
}

// K0b: all four weight splits in one launch. 2048 blocks of 256; each region
// is 512 blocks (131072 float4s).
__global__ __launch_bounds__(256) void split_weights(
    const float* __restrict__ Wq, const float* __restrict__ Wk,
    const float* __restrict__ Wv, const float* __restrict__ Wo,
    ushort* __restrict__ Wqkh, ushort* __restrict__ Wqkl,
    ushort* __restrict__ Wvh,  ushort* __restrict__ Wvl,
    ushort* __restrict__ Woh,  ushort* __restrict__ Wol)
{
    const int blk = blockIdx.x;
    const int region = blk >> 9;            // 0..3
    const int i = (blk & 511) * 256 + threadIdx.x;   // < 131072
    const float* src;
    ushort *dh, *dl;
    if (region == 0)      { src = Wq; dh = Wqkh;          dl = Wqkl; }
    else if (region == 1) { src = Wk; dh = Wqkh + 524288; dl = Wqkl + 524288; }
    else if (region == 2) { src = Wv; dh = Wvh;           dl = Wvl; }
    else                  { src = Wo; dh = Woh;           dl = Wol; }
    const float4 v = ((const float4*)src)[i];
    const float vv[4] = {v.x, v.y, v.z, v.w};
    uint hp[4], lp[4];
#pragma unroll
    for (int j = 0; j < 4; ++j) {
        const ushort hb = f2bf(vv[j]);
        hp[j] = hb;
        lp[j] = f2bf(vv[j] - bf2f(hb));
    }
    uint2 H, L;
    H.x = hp[0] | (hp[1] << 16); H.y = hp[2] | (hp[3] << 16);
    L.x = lp[0] | (lp[1] << 16); L.y = lp[2] | (lp[3] << 16);
    ((uint2*)dh)[i] = H;
    ((uint2*)dl)[i] = L;
}

// ---------------------------------------------------------------------------
// MFMA 3-pass hi/lo GEMM body (NT): C[m][n] = sum_k A[m][k]*B[n][k]
// BM=128, BN in {128,64}, BK=64, 256 threads = 4 waves (2x2), 16x16x32 bf16.
// Staging: global_load_lds w=16, source pre-swizzled ^(row&7) on 16B blocks.
// MODE 0: qk hi/lo split write; MODE 1: vt bf16 write; MODE 2: fp32 out+bias.
// ---------------------------------------------------------------------------
template<int BN, int KD, int MODE>
__device__ __forceinline__ void gemm3p_body(
    const ushort* __restrict__ Agh, const ushort* __restrict__ Agl,
    const ushort* __restrict__ Bgh, const ushort* __restrict__ Bgl,
    ushort* __restrict__ o0, ushort* __restrict__ o1,
    ushort* __restrict__ o2, ushort* __restrict__ o3,
    const float* __restrict__ bias, float* __restrict__ fo, int Ntiles)
{
    constexpr int NF = BN / 32;           // n-frags per wave
    __shared__ __align__(16) ushort Ah[128 * 64], Al[128 * 64];
    __shared__ __align__(16) ushort Bh[BN * 64],  Bl[BN * 64];

    const int cpx = gridDim.x >> 3;       // grid divisible by 8
    const int wg  = (blockIdx.x & 7) * cpx + (blockIdx.x >> 3);
    const int m0 = (wg / Ntiles) * 128;
    const int n0 = (wg % Ntiles) * BN;

    const int tid = threadIdx.x, w = tid >> 6, l = tid & 63;
    const int wr = w >> 1, wc = w & 1, g = l >> 4, c16 = l & 15;
    const int sr = l >> 3, sb = l & 7;    // staging: row-in-call, 16B block

    f32x4 acc[4][NF];
#pragma unroll
    for (int mi = 0; mi < 4; ++mi)
#pragma unroll
        for (int ni = 0; ni < NF; ++ni) acc[mi][ni] = (f32x4){0.f, 0.f, 0.f, 0.f};

    for (int k0 = 0; k0 < KD; k0 += 64) {
        __syncthreads();
        // ---- stage A (128 rows x 64 k, hi+lo) ----
#pragma unroll
        for (int j = 0; j < 4; ++j) {
            const int rb = w * 32 + j * 8;
            const int r  = rb + sr;
            const size_t src = (size_t)(m0 + r) * KD + k0 + ((sb ^ (r & 7)) * 8);
            __builtin_amdgcn_global_load_lds(Agh + src, &Ah[rb * 64], 16, 0, 0);
            __builtin_amdgcn_global_load_lds(Agl + src, &Al[rb * 64], 16, 0, 0);
        }
        // ---- stage B (BN rows x 64 k, hi+lo) ----
#pragma unroll
        for (int j = 0; j < BN / 32; ++j) {
            const int rb = w * (BN / 4) + j * 8;
            const int r  = rb + sr;
            const size_t src = (size_t)(n0 + r) * KD + k0 + ((sb ^ (r & 7)) * 8);
            __builtin_amdgcn_global_load_lds(Bgh + src, &Bh[rb * 64], 16, 0, 0);
            __builtin_amdgcn_global_load_lds(Bgl + src, &Bl[rb * 64], 16, 0, 0);
        }
        asm volatile("s_waitcnt vmcnt(0)" ::: "memory");
        __syncthreads();

#pragma unroll
        for (int kh = 0; kh < 2; ++kh) {
            const int bsel = ((kh << 2) | g) ^ (c16 & 7);
            short8 afh[4], afl[4], bfh[NF], bfl[NF];
#pragma unroll
            for (int mi = 0; mi < 4; ++mi) {
                const int row = wr * 64 + mi * 16 + c16;
                afh[mi] = *(const short8*)&Ah[row * 64 + bsel * 8];
                afl[mi] = *(const short8*)&Al[row * 64 + bsel * 8];
            }
#pragma unroll
            for (int ni = 0; ni < NF; ++ni) {
                const int row = wc * (BN / 2) + ni * 16 + c16;
                bfh[ni] = *(const short8*)&Bh[row * 64 + bsel * 8];
                bfl[ni] = *(const short8*)&Bl[row * 64 + bsel * 8];
            }
#pragma unroll
            for (int mi = 0; mi < 4; ++mi)
#pragma unroll
                for (int ni = 0; ni < NF; ++ni) {
                    acc[mi][ni] = __builtin_amdgcn_mfma_f32_16x16x32_bf16(afh[mi], bfh[ni], acc[mi][ni], 0, 0, 0);
                    acc[mi][ni] = __builtin_amdgcn_mfma_f32_16x16x32_bf16(afl[mi], bfh[ni], acc[mi][ni], 0, 0, 0);
                    acc[mi][ni] = __builtin_amdgcn_mfma_f32_16x16x32_bf16(afh[mi], bfl[ni], acc[mi][ni], 0, 0, 0);
                }
        }
    }

    // ---- epilogue ----
#pragma unroll
    for (int mi = 0; mi < 4; ++mi)
#pragma unroll
        for (int ni = 0; ni < NF; ++ni) {
            const int n = n0 + wc * (BN / 2) + ni * 16 + c16;
            if constexpr (MODE == 0) {
                const int op = n >> 11, hh = (n >> 8) & 7, d = n & 255;
                ushort* th = (op ? o2 : o0) + (size_t)hh * QE + d;
                ushort* tl = (op ? o3 : o1) + (size_t)hh * QE + d;
#pragma unroll
                for (int j = 0; j < 4; ++j) {
                    const int m = m0 + wr * 64 + mi * 16 + 4 * g + j;
                    const float v = acc[mi][ni][j];
                    const ushort hb = f2bf(v);
                    th[(size_t)m * 256] = hb;
                    tl[(size_t)m * 256] = f2bf(v - bf2f(hb));
                }
            } else if constexpr (MODE == 1) {
#pragma unroll
                for (int j = 0; j < 4; ++j) {
                    const int m = m0 + wr * 64 + mi * 16 + 4 * g + j;
                    o0[(size_t)m * NROWS + n] = f2bf(acc[mi][ni][j]);
                }
            } else {
                const float bb = bias[n];
#pragma unroll
                for (int j = 0; j < 4; ++j) {
                    const int m = m0 + wr * 64 + mi * 16 + 4 * g + j;
                    fo[(size_t)m * 256 + n] = acc[mi][ni][j] + bb;
                }
            }
        }
}

// Non-template wrappers (stubs emit correctly for extern "C" launch).
__global__ __launch_bounds__(256) void gemm_qk(
    const ushort* __restrict__ Agh, const ushort* __restrict__ Agl,
    const ushort* __restrict__ Bgh, const ushort* __restrict__ Bgl,
    ushort* __restrict__ qh, ushort* __restrict__ ql,
    ushort* __restrict__ kh, ushort* __restrict__ kl)
{
    gemm3p_body<128, 256, 0>(Agh, Agl, Bgh, Bgl, qh, ql, kh, kl, nullptr, nullptr, 32);
}

__global__ __launch_bounds__(256) void gemm_vt(
    const ushort* __restrict__ Agh, const ushort* __restrict__ Agl,
    const ushort* __restrict__ Bgh, const ushort* __restrict__ Bgl,
    ushort* __restrict__ vt)
{
    gemm3p_body<128, 256, 1>(Agh, Agl, Bgh, Bgl, vt, nullptr, nullptr, nullptr, nullptr, nullptr, 64);
}

__global__ __launch_bounds__(256) void gemm_out(
    const ushort* __restrict__ Agh, const ushort* __restrict__ Agl,
    const ushort* __restrict__ Bgh, const ushort* __restrict__ Bgl,
    const float* __restrict__ bias, float* __restrict__ fo)
{
    gemm3p_body<64, 2048, 2>(Agh, Agl, Bgh, Bgl, nullptr, nullptr, nullptr, nullptr, bias, fo, 4);
}

// ---------------------------------------------------------------------------
// K2: MFMA flash attention (swapped-operand form).
// Dispatch: HEAVY-FIRST (qt = 15 - (idx>>3)) to fix the causal-makespan tail
// (R4: OccupancyPercent=8.5%, heavy qt blocks launched last). hb-groups stay
// pinned per XCD for K/V L2 reuse.
// ---------------------------------------------------------------------------
__global__ __launch_bounds__(256) void flash_mfma(
    const ushort* __restrict__ qh, const ushort* __restrict__ ql,
    const ushort* __restrict__ kh, const ushort* __restrict__ kl,
    const ushort* __restrict__ vt,
    ushort* __restrict__ och, ushort* __restrict__ ocl)
{
    __shared__ __align__(16) ushort Khs[32 * 256];
    __shared__ __align__(16) ushort Kls[32 * 256];
    __shared__ __align__(16) ushort VTs[256 * 32];
    __shared__ __align__(16) ushort Pls[4 * 16 * 32];

    // heavy-first, XCD-local mapping
    const int bid = blockIdx.x;
    const int xcd = bid & 7;
    const int idx = bid >> 3;               // 0..127
    const int hb  = xcd * 8 + (idx & 7);    // 8 hb-groups per XCD
    const int qt  = 15 - (idx >> 3);        // heaviest q-tiles dispatch first
    const int h = hb >> 3, b = hb & 7;

    const int tid = threadIdx.x;
    const int w = tid >> 6, l = tid & 63;
    const int g = l >> 4, c16 = l & 15;
    const int qw0 = qt * 64 + w * 16;
    const int q_glob = qw0 + c16;
    const size_t qk_base = (size_t)h * QE + (size_t)b * (SEQ * EMBED);
    const size_t vt_base = (size_t)h * QE + (size_t)b * SEQ;

    short8 qfh[8], qfl[8];
    {
        const ushort* qr = qh + qk_base + (size_t)q_glob * EMBED + g * 8;
        const ushort* qs = ql + qk_base + (size_t)q_glob * EMBED + g * 8;
#pragma unroll
        for (int kc = 0; kc < 8; ++kc) {
            qfh[kc] = *(const short8*)(qr + kc * 32);
            qfl[kc] = *(const short8*)(qs + kc * 32);
        }
    }

    f32x4 acc[16];
#pragma unroll
    for (int dt = 0; dt < 16; ++dt) acc[dt] = (f32x4){0.f, 0.f, 0.f, 0.f};
    float m_r = -1e30f, l_r = 0.f;

    const int krow_l = l >> 5;
    const int kblk   = l & 31;
    const int vd_l   = l >> 2;
    const int vblk   = l & 3;

    const int nkt = 2 * qt + 2;
    for (int kt = 0; kt < nkt; ++kt) {
        __syncthreads();
#pragma unroll
        for (int j = 0; j < 4; ++j) {
            const int row = 8 * w + 2 * j + krow_l;
            const size_t src = qk_base + (size_t)(kt * 32 + row) * EMBED
                             + ((kblk ^ (row & 7)) * 8);
            __builtin_amdgcn_global_load_lds(kh + src, &Khs[(8 * w + 2 * j) * 256], 16, 0, 0);
            __builtin_amdgcn_global_load_lds(kl + src, &Kls[(8 * w + 2 * j) * 256], 16, 0, 0);
        }
#pragma unroll
        for (int j = 0; j < 4; ++j) {
            const int d = w * 64 + j * 16 + vd_l;
            const int phi = ((d >> 1) ^ (d >> 3)) & 3;
            const size_t src = vt_base + (size_t)d * NROWS + kt * 32
                             + ((vblk ^ phi) * 8);
            __builtin_amdgcn_global_load_lds(vt + src, &VTs[(w * 64 + j * 16) * 32], 16, 0, 0);
        }
        asm volatile("s_waitcnt vmcnt(0)" ::: "memory");
        __syncthreads();

        const bool active = (kt * 32 <= qw0 + 15);
        if (active) {
            f32x4 s0 = (f32x4){0.f, 0.f, 0.f, 0.f};
            f32x4 s1 = (f32x4){0.f, 0.f, 0.f, 0.f};
            const int rsw = c16 & 7;
#pragma unroll
            for (int kc = 0; kc < 8; ++kc) {
                const int blk = ((kc * 4 + g) ^ rsw) * 8;
                short8 a0h = *(const short8*)&Khs[c16 * 256 + blk];
                short8 a0l = *(const short8*)&Kls[c16 * 256 + blk];
                short8 a1h = *(const short8*)&Khs[(c16 + 16) * 256 + blk];
                short8 a1l = *(const short8*)&Kls[(c16 + 16) * 256 + blk];
                s0 = __builtin_amdgcn_mfma_f32_16x16x32_bf16(a0h, qfh[kc], s0, 0, 0, 0);
                s0 = __builtin_amdgcn_mfma_f32_16x16x32_bf16(a0l, qfh[kc], s0, 0, 0, 0);
                s0 = __builtin_amdgcn_mfma_f32_16x16x32_bf16(a0h, qfl[kc], s0, 0, 0, 0);
                s1 = __builtin_amdgcn_mfma_f32_16x16x32_bf16(a1h, qfh[kc], s1, 0, 0, 0);
                s1 = __builtin_amdgcn_mfma_f32_16x16x32_bf16(a1l, qfh[kc], s1, 0, 0, 0);
                s1 = __builtin_amdgcn_mfma_f32_16x16x32_bf16(a1h, qfl[kc], s1, 0, 0, 0);
            }
            const int k0b = kt * 32 + 4 * g;
            float p0[4], p1[4];
            float pm = -1e30f;
#pragma unroll
            for (int r = 0; r < 4; ++r) {
                p0[r] = (k0b + r      > q_glob) ? -1e30f : s0[r];
                p1[r] = (k0b + 16 + r > q_glob) ? -1e30f : s1[r];
                pm = fmaxf(pm, fmaxf(p0[r], p1[r]));
            }
            pm = fmaxf(pm, __shfl_xor(pm, 16));
            pm = fmaxf(pm, __shfl_xor(pm, 32));
            const float mnew = fmaxf(m_r, pm);
            const float sc = __expf(m_r - mnew);
            float ps = 0.f;
#pragma unroll
            for (int r = 0; r < 4; ++r) {
                p0[r] = __expf(p0[r] - mnew);
                p1[r] = __expf(p1[r] - mnew);
                ps += p0[r] + p1[r];
            }
            ps += __shfl_xor(ps, 16);
            ps += __shfl_xor(ps, 32);
            l_r = l_r * sc + ps;
            m_r = mnew;
#pragma unroll
            for (int dt = 0; dt < 16; ++dt) acc[dt] *= sc;

            char* pw = (char*)&Pls[w * 512];
            const int psw = (c16 >> 1) & 3;
#pragma unroll
            for (int t = 0; t < 2; ++t)
#pragma unroll
                for (int u = 0; u < 2; ++u) {
                    const float plo = t ? p1[2 * u] : p0[2 * u];
                    const float phi2 = t ? p1[2 * u + 1] : p0[2 * u + 1];
                    const uint pk = (uint)f2bf(plo) | ((uint)f2bf(phi2) << 16);
                    const int kk = 16 * t + 4 * g + 2 * u;
                    *(uint*)(pw + c16 * 64 + (((kk >> 3) ^ psw) * 16) + (kk & 7) * 2) = pk;
                }
            const short8 pfrag = *(const short8*)(pw + c16 * 64 + ((g ^ psw) * 16));

#pragma unroll
            for (int dt = 0; dt < 16; ++dt) {
                const int d = dt * 16 + c16;
                const int phi = ((d >> 1) ^ (d >> 3)) & 3;
                const short8 va = *(const short8*)&VTs[d * 32 + ((g ^ phi) * 8)];
                acc[dt] = __builtin_amdgcn_mfma_f32_16x16x32_bf16(va, pfrag, acc[dt], 0, 0, 0);
            }
        }
    }

    // ---- epilogue: och/ocl[b*SEQ+q][h*256+d] bf16 hi/lo ----
    const float inv = 1.f / l_r;
    const size_t obase = ((size_t)(b * SEQ) + q_glob) * (HEADS * EMBED) + h * EMBED;
#pragma unroll
    for (int dt = 0; dt < 16; ++dt) {
        const f32x4 o = acc[dt] * inv;
        uint hp[4], lp[4];
#pragma unroll
        for (int j = 0; j < 4; ++j) {
            const ushort hb2 = f2bf(o[j]);
            hp[j] = hb2;
            lp[j] = f2bf(o[j] - bf2f(hb2));
        }
        uint2 H, L;
        H.x = hp[0] | (hp[1] << 16); H.y = hp[2] | (hp[3] << 16);
        L.x = lp[0] | (lp[1] << 16); L.y = lp[2] | (lp[3] << 16);
        *(uint2*)(och + obase + dt * 16 + 4 * g) = H;
        *(uint2*)(ocl + obase + dt * 16 + 4 * g) = L;
    }
}

extern "C" void kernel_launch(void* const* d_in, const int* in_sizes, int n_in,
                              void* d_out, int out_size, void* d_ws, size_t ws_size,
                              hipStream_t stream) {
    const float* X  = (const float*)d_in[0];
    const float* Wq = (const float*)d_in[1];
    const float* Wk = (const float*)d_in[2];
    const float* Wv = (const float*)d_in[3];
    const float* Wo = (const float*)d_in[4];
    const float* bo = (const float*)d_in[5];

    ushort* ws16 = (ushort*)d_ws;
    ushort* qh   = ws16;                     // [8][8192][256] bf16
    ushort* ql   = ws16 +  8 * QE;
    ushort* kh   = ws16 + 16 * QE;
    ushort* kl   = ws16 + 24 * QE;
    ushort* vt   = ws16 + 32 * QE;           // [2048][8192] bf16
    ushort* och  = ws16 + 40 * QE;           // [8192][2048] bf16 hi
    ushort* ocl  = ws16 + 48 * QE;           // [8192][2048] bf16 lo
    ushort* ex   = ws16 + 56 * QE;           // extras
    ushort* Xh   = ex;                       // 2M
    ushort* Xl   = ex + 2097152;
    ushort* Wqkh = ex + 2 * 2097152;         // [4096][256] = 1M
    ushort* Wqkl = ex + 3 * 2097152;
    ushort* Wvh  = ex + 4 * 2097152;         // 0.5M
    ushort* Wvl  = ex + 4 * 2097152 + 524288;
    ushort* Woh  = ex + 5 * 2097152;         // [256][2048] = 0.5M
    ushort* Wol  = ex + 5 * 2097152 + 524288;
    float*  out  = (float*)d_out;

    // K0: splits (X + one merged weight-split launch)
    split_bf16<<<2048, 256, 0, stream>>>(X, Xh, Xl, 524288);
    split_weights<<<2048, 256, 0, stream>>>(Wq, Wk, Wv, Wo,
                                            Wqkh, Wqkl, Wvh, Wvl, Woh, Wol);

    // GEMM1: [8192x256] x [4096x256]^T -> qh/ql/kh/kl
    gemm_qk<<<2048, 256, 0, stream>>>(Xh, Xl, Wqkh, Wqkl, qh, ql, kh, kl);

    // GEMM2: vt[2048][8192] = Wv x X^T
    gemm_vt<<<1024, 256, 0, stream>>>(Wvh, Wvl, Xh, Xl, vt);

    // K2: flash attention (heavy-first dispatch)
    flash_mfma<<<1024, 256, 0, stream>>>(qh, ql, kh, kl, vt, och, ocl);

    // GEMM3: out[8192][256] = oc x Wo^T + bo
    gemm_out<<<256, 256, 0, stream>>>(och, ocl, Woh, Wol, bo, out);
}

// Round 6
// 248.615 us; speedup vs baseline: 15.9564x; 1.2635x over previous
//
#include <hip/hip_runtime.h>
#include <hip/hip_bf16.h>

#define EMBED 256
#define HEADS 8
#define BATCH 8
#define SEQ   1024
#define NROWS 8192

typedef __attribute__((ext_vector_type(8))) short short8;     // 8 bf16
typedef __attribute__((ext_vector_type(8))) _Float16 half8;   // 8 fp16
typedef __attribute__((ext_vector_type(4))) float f32x4;
typedef unsigned int  uint;
typedef unsigned short ushort;

#define QE   ((size_t)2097152)   /* per-head elems: 8192*256 */

__device__ __forceinline__ ushort f2bf(float f) {
    union { __hip_bfloat16 b; ushort u; } cv; cv.b = __float2bfloat16(f); return cv.u;
}
__device__ __forceinline__ float bf2f(ushort s) {
    union { ushort u; __hip_bfloat16 b; } cv; cv.u = s; return __bfloat162float(cv.b);
}
__device__ __forceinline__ ushort f2h(float f) {
    union { _Float16 h; ushort u; } cv; cv.h = (_Float16)f; return cv.u;
}

// ---------------------------------------------------------------------------
// K0a: X hi/lo bf16 split (float4-vectorized). n4 = elems/4.
// ---------------------------------------------------------------------------
__global__ __launch_bounds__(256) void split_bf16(
    const float* __restrict__ src, ushort* __restrict__ dh,
    ushort* __restrict__ dl, int n4)
{
    const int i = blockIdx.x * 256 + threadIdx.x;
    if (i >= n4) return;
    const float4 v = ((const float4*)src)[i];
    const float vv[4] = {v.x, v.y, v.z, v.w};
    uint hp[4], lp[4];
#pragma unroll
    for (int j = 0; j < 4; ++j) {
        const ushort hb = f2bf(vv[j]);
        hp[j] = hb;
        lp[j] = f2bf(vv[j] - bf2f(hb));
    }
    uint2 H, L;
    H.x = hp[0] | (hp[1] << 16); H.y = hp[2] | (hp[3] << 16);
    L.x = lp[0] | (lp[1] << 16); L.y = lp[2] | (lp[3] << 16);
    ((uint2*)dh)[i] = H;
    ((uint2*)dl)[i] = L;
}

// K0b: weight prep. Regions 0..2 (Wq,Wk,Wv): bf16 hi/lo split.
// Region 3 (Wo): fp16 single (outproj runs fp16 1-pass; K=2048 tiny weights).
__global__ __launch_bounds__(256) void split_weights(
    const float* __restrict__ Wq, const float* __restrict__ Wk,
    const float* __restrict__ Wv, const float* __restrict__ Wo,
    ushort* __restrict__ Wqkh, ushort* __restrict__ Wqkl,
    ushort* __restrict__ Wvh,  ushort* __restrict__ Wvl,
    ushort* __restrict__ Wof)
{
    const int blk = blockIdx.x;
    const int region = blk >> 9;            // 0..3
    const int i = (blk & 511) * 256 + threadIdx.x;   // < 131072 float4s
    if (region == 3) {
        const float4 v = ((const float4*)Wo)[i];
        uint2 P;
        P.x = (uint)f2h(v.x) | ((uint)f2h(v.y) << 16);
        P.y = (uint)f2h(v.z) | ((uint)f2h(v.w) << 16);
        ((uint2*)Wof)[i] = P;
        return;
    }
    const float* src; ushort *dh, *dl;
    if (region == 0)      { src = Wq; dh = Wqkh;          dl = Wqkl; }
    else if (region == 1) { src = Wk; dh = Wqkh + 524288; dl = Wqkl + 524288; }
    else                  { src = Wv; dh = Wvh;           dl = Wvl; }
    const float4 v = ((const float4*)src)[i];
    const float vv[4] = {v.x, v.y, v.z, v.w};
    uint hp[4], lp[4];
#pragma unroll
    for (int j = 0; j < 4; ++j) {
        const ushort hb = f2bf(vv[j]);
        hp[j] = hb;
        lp[j] = f2bf(vv[j] - bf2f(hb));
    }
    uint2 H, L;
    H.x = hp[0] | (hp[1] << 16); H.y = hp[2] | (hp[3] << 16);
    L.x = lp[0] | (lp[1] << 16); L.y = lp[2] | (lp[3] << 16);
    ((uint2*)dh)[i] = H;
    ((uint2*)dl)[i] = L;
}

// ---------------------------------------------------------------------------
// MFMA 3-pass hi/lo bf16 GEMM body (NT, fp32-accurate): emits FP16 outputs.
// BM=128, BN=128, BK=64, 256 threads = 4 waves (2x2), 16x16x32 bf16.
// MODE 0: q/k fp16 write (n: [q|k][head][d]); MODE 1: vt fp16 write.
// ---------------------------------------------------------------------------
template<int BN, int KD, int MODE>
__device__ __forceinline__ void gemm3p_body(
    const ushort* __restrict__ Agh, const ushort* __restrict__ Agl,
    const ushort* __restrict__ Bgh, const ushort* __restrict__ Bgl,
    ushort* __restrict__ o0, ushort* __restrict__ o1, int Ntiles)
{
    constexpr int NF = BN / 32;
    __shared__ __align__(16) ushort Ah[128 * 64], Al[128 * 64];
    __shared__ __align__(16) ushort Bh[BN * 64],  Bl[BN * 64];

    const int cpx = gridDim.x >> 3;
    const int wg  = (blockIdx.x & 7) * cpx + (blockIdx.x >> 3);
    const int m0 = (wg / Ntiles) * 128;
    const int n0 = (wg % Ntiles) * BN;

    const int tid = threadIdx.x, w = tid >> 6, l = tid & 63;
    const int wr = w >> 1, wc = w & 1, g = l >> 4, c16 = l & 15;
    const int sr = l >> 3, sb = l & 7;

    f32x4 acc[4][NF];
#pragma unroll
    for (int mi = 0; mi < 4; ++mi)
#pragma unroll
        for (int ni = 0; ni < NF; ++ni) acc[mi][ni] = (f32x4){0.f, 0.f, 0.f, 0.f};

    for (int k0 = 0; k0 < KD; k0 += 64) {
        __syncthreads();
#pragma unroll
        for (int j = 0; j < 4; ++j) {
            const int rb = w * 32 + j * 8;
            const int r  = rb + sr;
            const size_t src = (size_t)(m0 + r) * KD + k0 + ((sb ^ (r & 7)) * 8);
            __builtin_amdgcn_global_load_lds(Agh + src, &Ah[rb * 64], 16, 0, 0);
            __builtin_amdgcn_global_load_lds(Agl + src, &Al[rb * 64], 16, 0, 0);
        }
#pragma unroll
        for (int j = 0; j < BN / 32; ++j) {
            const int rb = w * (BN / 4) + j * 8;
            const int r  = rb + sr;
            const size_t src = (size_t)(n0 + r) * KD + k0 + ((sb ^ (r & 7)) * 8);
            __builtin_amdgcn_global_load_lds(Bgh + src, &Bh[rb * 64], 16, 0, 0);
            __builtin_amdgcn_global_load_lds(Bgl + src, &Bl[rb * 64], 16, 0, 0);
        }
        asm volatile("s_waitcnt vmcnt(0)" ::: "memory");
        __syncthreads();

#pragma unroll
        for (int kh = 0; kh < 2; ++kh) {
            const int bsel = ((kh << 2) | g) ^ (c16 & 7);
            short8 afh[4], afl[4], bfh[NF], bfl[NF];
#pragma unroll
            for (int mi = 0; mi < 4; ++mi) {
                const int row = wr * 64 + mi * 16 + c16;
                afh[mi] = *(const short8*)&Ah[row * 64 + bsel * 8];
                afl[mi] = *(const short8*)&Al[row * 64 + bsel * 8];
            }
#pragma unroll
            for (int ni = 0; ni < NF; ++ni) {
                const int row = wc * (BN / 2) + ni * 16 + c16;
                bfh[ni] = *(const short8*)&Bh[row * 64 + bsel * 8];
                bfl[ni] = *(const short8*)&Bl[row * 64 + bsel * 8];
            }
#pragma unroll
            for (int mi = 0; mi < 4; ++mi)
#pragma unroll
                for (int ni = 0; ni < NF; ++ni) {
                    acc[mi][ni] = __builtin_amdgcn_mfma_f32_16x16x32_bf16(afh[mi], bfh[ni], acc[mi][ni], 0, 0, 0);
                    acc[mi][ni] = __builtin_amdgcn_mfma_f32_16x16x32_bf16(afl[mi], bfh[ni], acc[mi][ni], 0, 0, 0);
                    acc[mi][ni] = __builtin_amdgcn_mfma_f32_16x16x32_bf16(afh[mi], bfl[ni], acc[mi][ni], 0, 0, 0);
                }
        }
    }

    // ---- epilogue: fp16 outputs ----
#pragma unroll
    for (int mi = 0; mi < 4; ++mi)
#pragma unroll
        for (int ni = 0; ni < NF; ++ni) {
            const int n = n0 + wc * (BN / 2) + ni * 16 + c16;
            if constexpr (MODE == 0) {
                const int op = n >> 11, hh = (n >> 8) & 7, d = n & 255;
                ushort* tq = (op ? o1 : o0) + (size_t)hh * QE + d;
#pragma unroll
                for (int j = 0; j < 4; ++j) {
                    const int m = m0 + wr * 64 + mi * 16 + 4 * g + j;
                    tq[(size_t)m * 256] = f2h(acc[mi][ni][j]);
                }
            } else {
#pragma unroll
                for (int j = 0; j < 4; ++j) {
                    const int m = m0 + wr * 64 + mi * 16 + 4 * g + j;
                    o0[(size_t)m * NROWS + n] = f2h(acc[mi][ni][j]);
                }
            }
        }
}

__global__ __launch_bounds__(256) void gemm_qk(
    const ushort* __restrict__ Agh, const ushort* __restrict__ Agl,
    const ushort* __restrict__ Bgh, const ushort* __restrict__ Bgl,
    ushort* __restrict__ qf, ushort* __restrict__ kf)
{
    gemm3p_body<128, 256, 0>(Agh, Agl, Bgh, Bgl, qf, kf, 32);
}

__global__ __launch_bounds__(256) void gemm_vt(
    const ushort* __restrict__ Agh, const ushort* __restrict__ Agl,
    const ushort* __restrict__ Bgh, const ushort* __restrict__ Bgl,
    ushort* __restrict__ vt)
{
    gemm3p_body<128, 256, 1>(Agh, Agl, Bgh, Bgl, vt, nullptr, 64);
}

// ---------------------------------------------------------------------------
// K3: fp16 single-pass output projection: out[8192][256] = ocf x Wof^T + bo.
// BM=128, BN=64, K=2048; grid 256 blocks (XCD-swizzled), 4 waves.
// ---------------------------------------------------------------------------
__global__ __launch_bounds__(256) void gemm_out_f16(
    const ushort* __restrict__ A, const ushort* __restrict__ Bw,
    const float* __restrict__ bias, float* __restrict__ fo)
{
    __shared__ __align__(16) ushort Ah[128 * 64];
    __shared__ __align__(16) ushort Bh[64 * 64];

    const int cpx = gridDim.x >> 3;
    const int wg  = (blockIdx.x & 7) * cpx + (blockIdx.x >> 3);
    const int m0 = (wg >> 2) * 128;
    const int n0 = (wg & 3) * 64;

    const int tid = threadIdx.x, w = tid >> 6, l = tid & 63;
    const int wr = w >> 1, wc = w & 1, g = l >> 4, c16 = l & 15;
    const int sr = l >> 3, sb = l & 7;

    f32x4 acc[4][2];
#pragma unroll
    for (int mi = 0; mi < 4; ++mi)
#pragma unroll
        for (int ni = 0; ni < 2; ++ni) acc[mi][ni] = (f32x4){0.f, 0.f, 0.f, 0.f};

    for (int k0 = 0; k0 < 2048; k0 += 64) {
        __syncthreads();
#pragma unroll
        for (int j = 0; j < 4; ++j) {
            const int rb = w * 32 + j * 8;
            const int r  = rb + sr;
            const size_t src = (size_t)(m0 + r) * 2048 + k0 + ((sb ^ (r & 7)) * 8);
            __builtin_amdgcn_global_load_lds(A + src, &Ah[rb * 64], 16, 0, 0);
        }
#pragma unroll
        for (int j = 0; j < 2; ++j) {
            const int rb = w * 16 + j * 8;
            const int r  = rb + sr;
            const size_t src = (size_t)(n0 + r) * 2048 + k0 + ((sb ^ (r & 7)) * 8);
            __builtin_amdgcn_global_load_lds(Bw + src, &Bh[rb * 64], 16, 0, 0);
        }
        asm volatile("s_waitcnt vmcnt(0)" ::: "memory");
        __syncthreads();

#pragma unroll
        for (int kh = 0; kh < 2; ++kh) {
            const int bsel = ((kh << 2) | g) ^ (c16 & 7);
            half8 af[4], bf[2];
#pragma unroll
            for (int mi = 0; mi < 4; ++mi)
                af[mi] = *(const half8*)&Ah[(wr * 64 + mi * 16 + c16) * 64 + bsel * 8];
#pragma unroll
            for (int ni = 0; ni < 2; ++ni)
                bf[ni] = *(const half8*)&Bh[(wc * 32 + ni * 16 + c16) * 64 + bsel * 8];
#pragma unroll
            for (int mi = 0; mi < 4; ++mi)
#pragma unroll
                for (int ni = 0; ni < 2; ++ni)
                    acc[mi][ni] = __builtin_amdgcn_mfma_f32_16x16x32_f16(af[mi], bf[ni], acc[mi][ni], 0, 0, 0);
        }
    }

#pragma unroll
    for (int mi = 0; mi < 4; ++mi)
#pragma unroll
        for (int ni = 0; ni < 2; ++ni) {
            const int n = n0 + wc * 32 + ni * 16 + c16;
            const float bb = bias[n];
#pragma unroll
            for (int j = 0; j < 4; ++j) {
                const int m = m0 + wr * 64 + mi * 16 + 4 * g + j;
                fo[(size_t)m * 256 + n] = acc[mi][ni][j] + bb;
            }
        }
}

// ---------------------------------------------------------------------------
// K2: fp16 MFMA flash attention (swapped-operand, single-pass).
// 512 blocks of uniform work: block = (hb, pair {15-pr, pr}) -> 36 k-tiles.
// 2 blocks/CU, LDS 68KB (double-buffered K + VT). Per wave-ktile: 16 K reads,
// 16 MFMA QK^T + 16 VT reads, 16 MFMA PV (was 49 reads / 64 MFMA).
// ---------------------------------------------------------------------------
__global__ __launch_bounds__(256) void flash_mfma(
    const ushort* __restrict__ qf, const ushort* __restrict__ kf,
    const ushort* __restrict__ vt, ushort* __restrict__ ocf)
{
    __shared__ __align__(16) ushort Ks[2][32 * 256];
    __shared__ __align__(16) ushort VTs[2][256 * 32];
    __shared__ __align__(16) ushort Pls[4 * 16 * 32];

    const int bid = blockIdx.x;
    const int xcd = bid & 7;
    const int idx = bid >> 3;               // 0..63
    const int hb  = xcd * 8 + (idx & 7);    // same-XCD hb groups share K/V in L2
    const int pr  = idx >> 3;               // 0..7
    const int h = hb >> 3, b = hb & 7;

    const int tid = threadIdx.x;
    const int w = tid >> 6, l = tid & 63;
    const int g = l >> 4, c16 = l & 15;
    const size_t qk_base = (size_t)h * QE + (size_t)b * (SEQ * EMBED);
    const size_t vt_base = (size_t)h * QE + (size_t)b * SEQ;

    const int krow_l = l >> 5, kblk = l & 31;
    const int vd_l = l >> 2,  vblk = l & 3;
    const int rsw = c16 & 7;
    const int psw = (c16 >> 1) & 3;
    char* pw = (char*)&Pls[w * 512];

    auto stage = [&](int kt, int bufi) {
#pragma unroll
        for (int j = 0; j < 4; ++j) {
            const int row = 8 * w + 2 * j + krow_l;
            const size_t src = qk_base + (size_t)(kt * 32 + row) * EMBED
                             + ((kblk ^ (row & 7)) * 8);
            __builtin_amdgcn_global_load_lds(kf + src, &Ks[bufi][(8 * w + 2 * j) * 256], 16, 0, 0);
        }
#pragma unroll
        for (int j = 0; j < 4; ++j) {
            const int d = w * 64 + j * 16 + vd_l;
            const int phi = ((d >> 1) ^ (d >> 3)) & 3;
            const size_t src = vt_base + (size_t)d * NROWS + kt * 32
                             + ((vblk ^ phi) * 8);
            __builtin_amdgcn_global_load_lds(vt + src, &VTs[bufi][(w * 64 + j * 16) * 32], 16, 0, 0);
        }
    };

    for (int seg = 0; seg < 2; ++seg) {
        const int qt = (seg == 0) ? (15 - pr) : pr;
        const int qw0 = qt * 64 + w * 16;
        const int q_glob = qw0 + c16;

        half8 qfr[8];
        {
            const ushort* qr = qf + qk_base + (size_t)q_glob * EMBED + g * 8;
#pragma unroll
            for (int kc = 0; kc < 8; ++kc)
                qfr[kc] = *(const half8*)(qr + kc * 32);
        }

        f32x4 acc[16];
#pragma unroll
        for (int dt = 0; dt < 16; ++dt) acc[dt] = (f32x4){0.f, 0.f, 0.f, 0.f};
        float m_r = -1e30f, l_r = 0.f;

        const int nkt = 2 * qt + 2;
        int cur = 0;
        stage(0, 0);
        asm volatile("s_waitcnt vmcnt(0)" ::: "memory");
        __syncthreads();

        for (int kt = 0; kt < nkt; ++kt) {
            if (kt + 1 < nkt) stage(kt + 1, cur ^ 1);   // prefetch overlaps compute

            if (kt * 32 <= qw0 + 15) {
                const ushort* Kb = &Ks[cur][0];
                const ushort* Vb = &VTs[cur][0];
                f32x4 s0 = (f32x4){0.f, 0.f, 0.f, 0.f};
                f32x4 s1 = (f32x4){0.f, 0.f, 0.f, 0.f};
#pragma unroll
                for (int kc = 0; kc < 8; ++kc) {
                    const int blk = ((kc * 4 + g) ^ rsw) * 8;
                    half8 a0 = *(const half8*)&Kb[c16 * 256 + blk];
                    half8 a1 = *(const half8*)&Kb[(c16 + 16) * 256 + blk];
                    s0 = __builtin_amdgcn_mfma_f32_16x16x32_f16(a0, qfr[kc], s0, 0, 0, 0);
                    s1 = __builtin_amdgcn_mfma_f32_16x16x32_f16(a1, qfr[kc], s1, 0, 0, 0);
                }
                const int k0b = kt * 32 + 4 * g;
                float p0[4], p1[4];
                float pm = -1e30f;
#pragma unroll
                for (int r = 0; r < 4; ++r) {
                    p0[r] = (k0b + r      > q_glob) ? -1e30f : s0[r];
                    p1[r] = (k0b + 16 + r > q_glob) ? -1e30f : s1[r];
                    pm = fmaxf(pm, fmaxf(p0[r], p1[r]));
                }
                pm = fmaxf(pm, __shfl_xor(pm, 16));
                pm = fmaxf(pm, __shfl_xor(pm, 32));
                const float mnew = fmaxf(m_r, pm);
                const float sc = __expf(m_r - mnew);
                float ps = 0.f;
#pragma unroll
                for (int r = 0; r < 4; ++r) {
                    p0[r] = __expf(p0[r] - mnew);
                    p1[r] = __expf(p1[r] - mnew);
                    ps += p0[r] + p1[r];
                }
                ps += __shfl_xor(ps, 16);
                ps += __shfl_xor(ps, 32);
                l_r = l_r * sc + ps;
                m_r = mnew;
#pragma unroll
                for (int dt = 0; dt < 16; ++dt) acc[dt] *= sc;

                // P bounce (fp16): C-layout -> B-fragment via per-wave LDS
#pragma unroll
                for (int t = 0; t < 2; ++t)
#pragma unroll
                    for (int u = 0; u < 2; ++u) {
                        const float plo = t ? p1[2 * u] : p0[2 * u];
                        const float phi2 = t ? p1[2 * u + 1] : p0[2 * u + 1];
                        const uint pk = (uint)f2h(plo) | ((uint)f2h(phi2) << 16);
                        const int kk = 16 * t + 4 * g + 2 * u;
                        *(uint*)(pw + c16 * 64 + (((kk >> 3) ^ psw) * 16) + (kk & 7) * 2) = pk;
                    }
                const half8 pfrag = *(const half8*)(pw + c16 * 64 + ((g ^ psw) * 16));

#pragma unroll
                for (int dt = 0; dt < 16; ++dt) {
                    const int d = dt * 16 + c16;
                    const int phi = ((d >> 1) ^ (d >> 3)) & 3;
                    const half8 va = *(const half8*)&Vb[d * 32 + ((g ^ phi) * 8)];
                    acc[dt] = __builtin_amdgcn_mfma_f32_16x16x32_f16(va, pfrag, acc[dt], 0, 0, 0);
                }
            }
            asm volatile("s_waitcnt vmcnt(0)" ::: "memory");
            __syncthreads();
            cur ^= 1;
        }

        // ---- epilogue: ocf[b*SEQ+q][h*256+d] fp16 ----
        const float inv = 1.f / l_r;
        ushort* orow = ocf + ((size_t)(b * SEQ) + q_glob) * (HEADS * EMBED) + h * EMBED;
#pragma unroll
        for (int dt = 0; dt < 16; ++dt) {
            const f32x4 o = acc[dt] * inv;
            uint2 P2;
            P2.x = (uint)f2h(o[0]) | ((uint)f2h(o[1]) << 16);
            P2.y = (uint)f2h(o[2]) | ((uint)f2h(o[3]) << 16);
            *(uint2*)(orow + dt * 16 + 4 * g) = P2;
        }
    }
}

extern "C" void kernel_launch(void* const* d_in, const int* in_sizes, int n_in,
                              void* d_out, int out_size, void* d_ws, size_t ws_size,
                              hipStream_t stream) {
    const float* X  = (const float*)d_in[0];
    const float* Wq = (const float*)d_in[1];
    const float* Wk = (const float*)d_in[2];
    const float* Wv = (const float*)d_in[3];
    const float* Wo = (const float*)d_in[4];
    const float* bo = (const float*)d_in[5];

    ushort* ws16 = (ushort*)d_ws;
    ushort* qf   = ws16;                     // [8][8192][256] fp16
    ushort* kf   = ws16 +  8 * QE;           // fp16
    ushort* vtb  = ws16 + 16 * QE;           // [8][256][8192] fp16
    ushort* ocf  = ws16 + 24 * QE;           // [8192][2048] fp16
    ushort* ex   = ws16 + 32 * QE;
    ushort* Xh   = ex;                       // 2M bf16
    ushort* Xl   = ex + 2097152;
    ushort* Wqkh = ex + 2 * 2097152;         // [4096][256] bf16
    ushort* Wqkl = ex + 3 * 2097152;
    ushort* Wvh  = ex + 4 * 2097152;
    ushort* Wvl  = ex + 4 * 2097152 + 524288;
    ushort* Wof  = ex + 5 * 2097152;         // [256][2048] fp16
    float*  out  = (float*)d_out;

    split_bf16<<<2048, 256, 0, stream>>>(X, Xh, Xl, 524288);
    split_weights<<<2048, 256, 0, stream>>>(Wq, Wk, Wv, Wo,
                                            Wqkh, Wqkl, Wvh, Wvl, Wof);

    // GEMM1: [8192x256] x [4096x256]^T -> qf/kf (fp16)
    gemm_qk<<<2048, 256, 0, stream>>>(Xh, Xl, Wqkh, Wqkl, qf, kf);

    // GEMM2: vt[2048][8192] = Wv x X^T (fp16)
    gemm_vt<<<1024, 256, 0, stream>>>(Wvh, Wvl, Xh, Xl, vtb);

    // K2: flash attention (uniform-work paired blocks)
    flash_mfma<<<512, 256, 0, stream>>>(qf, kf, vtb, ocf);

    // K3: out[8192][256] = ocf x Wof^T + bo (fp16 single-pass)
    gemm_out_f16<<<256, 256, 0, stream>>>(ocf, Wof, bo, out);
}

// Round 8
// 245.561 us; speedup vs baseline: 16.1548x; 1.0124x over previous
//
#include <hip/hip_runtime.h>
#include <hip/hip_bf16.h>

#define EMBED 256
#define HEADS 8
#define BATCH 8
#define SEQ   1024
#define NROWS 8192

typedef __attribute__((ext_vector_type(8))) short short8;     // 8 bf16
typedef __attribute__((ext_vector_type(8))) _Float16 half8;   // 8 fp16
typedef __attribute__((ext_vector_type(4))) float f32x4;
typedef unsigned int  uint;
typedef unsigned short ushort;

#define QE   ((size_t)2097152)   /* per-head elems: 8192*256 */

__device__ __forceinline__ ushort f2bf(float f) {
    union { __hip_bfloat16 b; ushort u; } cv; cv.b = __float2bfloat16(f); return cv.u;
}
__device__ __forceinline__ float bf2f(ushort s) {
    union { ushort u; __hip_bfloat16 b; } cv; cv.u = s; return __bfloat162float(cv.b);
}
__device__ __forceinline__ ushort f2h(float f) {
    union { _Float16 h; ushort u; } cv; cv.h = (_Float16)f; return cv.u;
}

// ---------------------------------------------------------------------------
// K0a: X hi/lo bf16 split (float4-vectorized). n4 = elems/4.
// ---------------------------------------------------------------------------
__global__ __launch_bounds__(256) void split_bf16(
    const float* __restrict__ src, ushort* __restrict__ dh,
    ushort* __restrict__ dl, int n4)
{
    const int i = blockIdx.x * 256 + threadIdx.x;
    if (i >= n4) return;
    const float4 v = ((const float4*)src)[i];
    const float vv[4] = {v.x, v.y, v.z, v.w};
    uint hp[4], lp[4];
#pragma unroll
    for (int j = 0; j < 4; ++j) {
        const ushort hb = f2bf(vv[j]);
        hp[j] = hb;
        lp[j] = f2bf(vv[j] - bf2f(hb));
    }
    uint2 H, L;
    H.x = hp[0] | (hp[1] << 16); H.y = hp[2] | (hp[3] << 16);
    L.x = lp[0] | (lp[1] << 16); L.y = lp[2] | (lp[3] << 16);
    ((uint2*)dh)[i] = H;
    ((uint2*)dl)[i] = L;
}

// K0b: weight prep. Regions 0..2 (Wq,Wk,Wv): bf16 hi/lo split.
// Region 3 (Wo): fp16 single.
__global__ __launch_bounds__(256) void split_weights(
    const float* __restrict__ Wq, const float* __restrict__ Wk,
    const float* __restrict__ Wv, const float* __restrict__ Wo,
    ushort* __restrict__ Wqkh, ushort* __restrict__ Wqkl,
    ushort* __restrict__ Wvh,  ushort* __restrict__ Wvl,
    ushort* __restrict__ Wof)
{
    const int blk = blockIdx.x;
    const int region = blk >> 9;            // 0..3
    const int i = (blk & 511) * 256 + threadIdx.x;   // < 131072 float4s
    if (region == 3) {
        const float4 v = ((const float4*)Wo)[i];
        uint2 P;
        P.x = (uint)f2h(v.x) | ((uint)f2h(v.y) << 16);
        P.y = (uint)f2h(v.z) | ((uint)f2h(v.w) << 16);
        ((uint2*)Wof)[i] = P;
        return;
    }
    const float* src; ushort *dh, *dl;
    if (region == 0)      { src = Wq; dh = Wqkh;          dl = Wqkl; }
    else if (region == 1) { src = Wk; dh = Wqkh + 524288; dl = Wqkl + 524288; }
    else                  { src = Wv; dh = Wvh;           dl = Wvl; }
    const float4 v = ((const float4*)src)[i];
    const float vv[4] = {v.x, v.y, v.z, v.w};
    uint hp[4], lp[4];
#pragma unroll
    for (int j = 0; j < 4; ++j) {
        const ushort hb = f2bf(vv[j]);
        hp[j] = hb;
        lp[j] = f2bf(vv[j] - bf2f(hb));
    }
    uint2 H, L;
    H.x = hp[0] | (hp[1] << 16); H.y = hp[2] | (hp[3] << 16);
    L.x = lp[0] | (lp[1] << 16); L.y = lp[2] | (lp[3] << 16);
    ((uint2*)dh)[i] = H;
    ((uint2*)dl)[i] = L;
}

// ---------------------------------------------------------------------------
// MFMA 3-pass hi/lo bf16 GEMM body (NT, fp32-accurate): emits FP16 outputs.
// BM=128, BN=128, BK=64, 256 threads = 4 waves (2x2), 16x16x32 bf16.
// MODE 0: q/k fp16 write; MODE 1: vt fp16 write.
// ---------------------------------------------------------------------------
template<int BN, int KD, int MODE>
__device__ __forceinline__ void gemm3p_body(
    const ushort* __restrict__ Agh, const ushort* __restrict__ Agl,
    const ushort* __restrict__ Bgh, const ushort* __restrict__ Bgl,
    ushort* __restrict__ o0, ushort* __restrict__ o1, int Ntiles)
{
    constexpr int NF = BN / 32;
    __shared__ __align__(16) ushort Ah[128 * 64], Al[128 * 64];
    __shared__ __align__(16) ushort Bh[BN * 64],  Bl[BN * 64];

    const int cpx = gridDim.x >> 3;
    const int wg  = (blockIdx.x & 7) * cpx + (blockIdx.x >> 3);
    const int m0 = (wg / Ntiles) * 128;
    const int n0 = (wg % Ntiles) * BN;

    const int tid = threadIdx.x, w = tid >> 6, l = tid & 63;
    const int wr = w >> 1, wc = w & 1, g = l >> 4, c16 = l & 15;
    const int sr = l >> 3, sb = l & 7;

    f32x4 acc[4][NF];
#pragma unroll
    for (int mi = 0; mi < 4; ++mi)
#pragma unroll
        for (int ni = 0; ni < NF; ++ni) acc[mi][ni] = (f32x4){0.f, 0.f, 0.f, 0.f};

    for (int k0 = 0; k0 < KD; k0 += 64) {
        __syncthreads();
#pragma unroll
        for (int j = 0; j < 4; ++j) {
            const int rb = w * 32 + j * 8;
            const int r  = rb + sr;
            const size_t src = (size_t)(m0 + r) * KD + k0 + ((sb ^ (r & 7)) * 8);
            __builtin_amdgcn_global_load_lds(Agh + src, &Ah[rb * 64], 16, 0, 0);
            __builtin_amdgcn_global_load_lds(Agl + src, &Al[rb * 64], 16, 0, 0);
        }
#pragma unroll
        for (int j = 0; j < BN / 32; ++j) {
            const int rb = w * (BN / 4) + j * 8;
            const int r  = rb + sr;
            const size_t src = (size_t)(n0 + r) * KD + k0 + ((sb ^ (r & 7)) * 8);
            __builtin_amdgcn_global_load_lds(Bgh + src, &Bh[rb * 64], 16, 0, 0);
            __builtin_amdgcn_global_load_lds(Bgl + src, &Bl[rb * 64], 16, 0, 0);
        }
        asm volatile("s_waitcnt vmcnt(0)" ::: "memory");
        __syncthreads();

#pragma unroll
        for (int kh = 0; kh < 2; ++kh) {
            const int bsel = ((kh << 2) | g) ^ (c16 & 7);
            short8 afh[4], afl[4], bfh[NF], bfl[NF];
#pragma unroll
            for (int mi = 0; mi < 4; ++mi) {
                const int row = wr * 64 + mi * 16 + c16;
                afh[mi] = *(const short8*)&Ah[row * 64 + bsel * 8];
                afl[mi] = *(const short8*)&Al[row * 64 + bsel * 8];
            }
#pragma unroll
            for (int ni = 0; ni < NF; ++ni) {
                const int row = wc * (BN / 2) + ni * 16 + c16;
                bfh[ni] = *(const short8*)&Bh[row * 64 + bsel * 8];
                bfl[ni] = *(const short8*)&Bl[row * 64 + bsel * 8];
            }
#pragma unroll
            for (int mi = 0; mi < 4; ++mi)
#pragma unroll
                for (int ni = 0; ni < NF; ++ni) {
                    acc[mi][ni] = __builtin_amdgcn_mfma_f32_16x16x32_bf16(afh[mi], bfh[ni], acc[mi][ni], 0, 0, 0);
                    acc[mi][ni] = __builtin_amdgcn_mfma_f32_16x16x32_bf16(afl[mi], bfh[ni], acc[mi][ni], 0, 0, 0);
                    acc[mi][ni] = __builtin_amdgcn_mfma_f32_16x16x32_bf16(afh[mi], bfl[ni], acc[mi][ni], 0, 0, 0);
                }
        }
    }

#pragma unroll
    for (int mi = 0; mi < 4; ++mi)
#pragma unroll
        for (int ni = 0; ni < NF; ++ni) {
            const int n = n0 + wc * (BN / 2) + ni * 16 + c16;
            if constexpr (MODE == 0) {
                const int op = n >> 11, hh = (n >> 8) & 7, d = n & 255;
                ushort* tq = (op ? o1 : o0) + (size_t)hh * QE + d;
#pragma unroll
                for (int j = 0; j < 4; ++j) {
                    const int m = m0 + wr * 64 + mi * 16 + 4 * g + j;
                    tq[(size_t)m * 256] = f2h(acc[mi][ni][j]);
                }
            } else {
#pragma unroll
                for (int j = 0; j < 4; ++j) {
                    const int m = m0 + wr * 64 + mi * 16 + 4 * g + j;
                    o0[(size_t)m * NROWS + n] = f2h(acc[mi][ni][j]);
                }
            }
        }
}

__global__ __launch_bounds__(256) void gemm_qk(
    const ushort* __restrict__ Agh, const ushort* __restrict__ Agl,
    const ushort* __restrict__ Bgh, const ushort* __restrict__ Bgl,
    ushort* __restrict__ qf, ushort* __restrict__ kf)
{
    gemm3p_body<128, 256, 0>(Agh, Agl, Bgh, Bgl, qf, kf, 32);
}

__global__ __launch_bounds__(256) void gemm_vt(
    const ushort* __restrict__ Agh, const ushort* __restrict__ Agl,
    const ushort* __restrict__ Bgh, const ushort* __restrict__ Bgl,
    ushort* __restrict__ vt)
{
    gemm3p_body<128, 256, 1>(Agh, Agl, Bgh, Bgl, vt, nullptr, 64);
}

// ---------------------------------------------------------------------------
// K3: fp16 single-pass output projection: out[8192][256] = ocf x Wof^T + bo.
// ---------------------------------------------------------------------------
__global__ __launch_bounds__(256) void gemm_out_f16(
    const ushort* __restrict__ A, const ushort* __restrict__ Bw,
    const float* __restrict__ bias, float* __restrict__ fo)
{
    __shared__ __align__(16) ushort Ah[128 * 64];
    __shared__ __align__(16) ushort Bh[64 * 64];

    const int cpx = gridDim.x >> 3;
    const int wg  = (blockIdx.x & 7) * cpx + (blockIdx.x >> 3);
    const int m0 = (wg >> 2) * 128;
    const int n0 = (wg & 3) * 64;

    const int tid = threadIdx.x, w = tid >> 6, l = tid & 63;
    const int wr = w >> 1, wc = w & 1, g = l >> 4, c16 = l & 15;
    const int sr = l >> 3, sb = l & 7;

    f32x4 acc[4][2];
#pragma unroll
    for (int mi = 0; mi < 4; ++mi)
#pragma unroll
        for (int ni = 0; ni < 2; ++ni) acc[mi][ni] = (f32x4){0.f, 0.f, 0.f, 0.f};

    for (int k0 = 0; k0 < 2048; k0 += 64) {
        __syncthreads();
#pragma unroll
        for (int j = 0; j < 4; ++j) {
            const int rb = w * 32 + j * 8;
            const int r  = rb + sr;
            const size_t src = (size_t)(m0 + r) * 2048 + k0 + ((sb ^ (r & 7)) * 8);
            __builtin_amdgcn_global_load_lds(A + src, &Ah[rb * 64], 16, 0, 0);
        }
#pragma unroll
        for (int j = 0; j < 2; ++j) {
            const int rb = w * 16 + j * 8;
            const int r  = rb + sr;
            const size_t src = (size_t)(n0 + r) * 2048 + k0 + ((sb ^ (r & 7)) * 8);
            __builtin_amdgcn_global_load_lds(Bw + src, &Bh[rb * 64], 16, 0, 0);
        }
        asm volatile("s_waitcnt vmcnt(0)" ::: "memory");
        __syncthreads();

#pragma unroll
        for (int kh = 0; kh < 2; ++kh) {
            const int bsel = ((kh << 2) | g) ^ (c16 & 7);
            half8 af[4], bf[2];
#pragma unroll
            for (int mi = 0; mi < 4; ++mi)
                af[mi] = *(const half8*)&Ah[(wr * 64 + mi * 16 + c16) * 64 + bsel * 8];
#pragma unroll
            for (int ni = 0; ni < 2; ++ni)
                bf[ni] = *(const half8*)&Bh[(wc * 32 + ni * 16 + c16) * 64 + bsel * 8];
#pragma unroll
            for (int mi = 0; mi < 4; ++mi)
#pragma unroll
                for (int ni = 0; ni < 2; ++ni)
                    acc[mi][ni] = __builtin_amdgcn_mfma_f32_16x16x32_f16(af[mi], bf[ni], acc[mi][ni], 0, 0, 0);
        }
    }

#pragma unroll
    for (int mi = 0; mi < 4; ++mi)
#pragma unroll
        for (int ni = 0; ni < 2; ++ni) {
            const int n = n0 + wc * 32 + ni * 16 + c16;
            const float bb = bias[n];
#pragma unroll
            for (int j = 0; j < 4; ++j) {
                const int m = m0 + wr * 64 + mi * 16 + 4 * g + j;
                fo[(size_t)m * 256 + n] = acc[mi][ni][j] + bb;
            }
        }
}

// ---------------------------------------------------------------------------
// K2: fp16 MFMA flash attention — 32 q-rows per wave (2 q-blocks), 128 q/block.
// 512 blocks = 64 hb x 8 qst, heavy-first (qst desc), hb pinned per XCD.
// Per wave-ktile: 16 K reads -> 32 QK MFMA; 16 VT reads -> 32 PV MFMA (2:1).
// Defer-rescale (T13, THR=8). LDS 72KB -> 2 blocks/CU.
// P-bounce areas are 1024 B per (wave, q-block): Pls[4][2][512] ushorts.
// (R7 bug: [4][2][256] = 512 B/area overflowed -> absmax 4160.)
// ---------------------------------------------------------------------------
__global__ __launch_bounds__(256, 2) void flash_mfma(
    const ushort* __restrict__ qf, const ushort* __restrict__ kf,
    const ushort* __restrict__ vt, ushort* __restrict__ ocf)
{
    __shared__ __align__(16) ushort Ks[2][32 * 256];
    __shared__ __align__(16) ushort VTs[2][256 * 32];
    __shared__ __align__(16) ushort Pls[4][2][512];

    const int bid = blockIdx.x;
    const int hb  = (bid & 7) * 8 + ((bid >> 3) & 7);  // same-hb on same XCD
    const int qst = 7 - (bid >> 6);                    // heavy-first
    const int h = hb >> 3, b = hb & 7;

    const int tid = threadIdx.x;
    const int w = tid >> 6, l = tid & 63;
    const int g = l >> 4, c16 = l & 15;
    const size_t qk_base = (size_t)h * QE + (size_t)b * (SEQ * EMBED);
    const size_t vt_base = (size_t)h * QE + (size_t)b * SEQ;

    const int krow_l = l >> 5, kblk = l & 31;
    const int vd_l = l >> 2,  vblk = l & 3;
    const int rsw = c16 & 7;
    const int psw = (c16 >> 1) & 3;

    const int qw0 = qst * 128 + w * 32;
    const int q0 = qw0 + c16;
    const int q1 = qw0 + 16 + c16;

    // Q fragments for both q-blocks (held in regs)
    half8 qfr0[8], qfr1[8];
    {
        const ushort* qr0 = qf + qk_base + (size_t)q0 * EMBED + g * 8;
        const ushort* qr1 = qf + qk_base + (size_t)q1 * EMBED + g * 8;
#pragma unroll
        for (int kc = 0; kc < 8; ++kc) {
            qfr0[kc] = *(const half8*)(qr0 + kc * 32);
            qfr1[kc] = *(const half8*)(qr1 + kc * 32);
        }
    }

    // staging source pointers (advance by constants per ktile)
    const ushort* kptr[4];
    const ushort* vptr[4];
#pragma unroll
    for (int j = 0; j < 4; ++j) {
        const int row = 8 * w + 2 * j + krow_l;
        kptr[j] = kf + qk_base + (size_t)row * EMBED + ((kblk ^ (row & 7)) * 8);
        const int d = w * 64 + j * 16 + vd_l;
        const int phi = ((d >> 1) ^ (d >> 3)) & 3;
        vptr[j] = vt + vt_base + (size_t)d * NROWS + ((vblk ^ phi) * 8);
    }

    f32x4 acc0[16], acc1[16];
#pragma unroll
    for (int dt = 0; dt < 16; ++dt) {
        acc0[dt] = (f32x4){0.f, 0.f, 0.f, 0.f};
        acc1[dt] = (f32x4){0.f, 0.f, 0.f, 0.f};
    }
    float m0r = -1e30f, l0r = 0.f, m1r = -1e30f, l1r = 0.f;

    const int nkt = 4 * qst + 4;

    // prologue stage tile 0 into buf 0
#pragma unroll
    for (int j = 0; j < 4; ++j) {
        __builtin_amdgcn_global_load_lds(kptr[j], &Ks[0][(8 * w + 2 * j) * 256], 16, 0, 0);
        kptr[j] += 32 * EMBED;
        __builtin_amdgcn_global_load_lds(vptr[j], &VTs[0][(w * 64 + j * 16) * 32], 16, 0, 0);
        vptr[j] += 32;
    }
    asm volatile("s_waitcnt vmcnt(0)" ::: "memory");
    __syncthreads();

    int cur = 0;
    for (int kt = 0; kt < nkt; ++kt) {
        if (kt + 1 < nkt) {
            const int nb = cur ^ 1;
#pragma unroll
            for (int j = 0; j < 4; ++j) {
                __builtin_amdgcn_global_load_lds(kptr[j], &Ks[nb][(8 * w + 2 * j) * 256], 16, 0, 0);
                kptr[j] += 32 * EMBED;
                __builtin_amdgcn_global_load_lds(vptr[j], &VTs[nb][(w * 64 + j * 16) * 32], 16, 0, 0);
                vptr[j] += 32;
            }
        }

        if (kt * 32 <= qw0 + 31) {
            const ushort* Kb = &Ks[cur][0];
            const ushort* Vb = &VTs[cur][0];
            f32x4 s00 = (f32x4){0.f,0.f,0.f,0.f}, s01 = s00, s10 = s00, s11 = s00;
#pragma unroll
            for (int kc = 0; kc < 8; ++kc) {
                const int blk = ((kc * 4 + g) ^ rsw) * 8;
                const half8 a0 = *(const half8*)&Kb[c16 * 256 + blk];
                const half8 a1 = *(const half8*)&Kb[(c16 + 16) * 256 + blk];
                s00 = __builtin_amdgcn_mfma_f32_16x16x32_f16(a0, qfr0[kc], s00, 0, 0, 0);
                s01 = __builtin_amdgcn_mfma_f32_16x16x32_f16(a0, qfr1[kc], s01, 0, 0, 0);
                s10 = __builtin_amdgcn_mfma_f32_16x16x32_f16(a1, qfr0[kc], s10, 0, 0, 0);
                s11 = __builtin_amdgcn_mfma_f32_16x16x32_f16(a1, qfr1[kc], s11, 0, 0, 0);
            }
            const int k0b = kt * 32 + 4 * g;
            float p00[4], p10[4], p01[4], p11[4];
            float pm0 = -1e30f, pm1 = -1e30f;
#pragma unroll
            for (int r = 0; r < 4; ++r) {
                p00[r] = (k0b + r      > q0) ? -1e30f : s00[r];
                p10[r] = (k0b + 16 + r > q0) ? -1e30f : s10[r];
                p01[r] = (k0b + r      > q1) ? -1e30f : s01[r];
                p11[r] = (k0b + 16 + r > q1) ? -1e30f : s11[r];
                pm0 = fmaxf(pm0, fmaxf(p00[r], p10[r]));
                pm1 = fmaxf(pm1, fmaxf(p01[r], p11[r]));
            }
            pm0 = fmaxf(pm0, __shfl_xor(pm0, 16));
            pm0 = fmaxf(pm0, __shfl_xor(pm0, 32));
            pm1 = fmaxf(pm1, __shfl_xor(pm1, 16));
            pm1 = fmaxf(pm1, __shfl_xor(pm1, 32));

            // T13 defer-rescale: only rescale when max grew past THR=8
            if (__any((pm0 > m0r + 8.f) || (pm1 > m1r + 8.f))) {
                const float m0n = fmaxf(m0r, pm0);
                const float m1n = fmaxf(m1r, pm1);
                const float sc0 = __expf(m0r - m0n);
                const float sc1 = __expf(m1r - m1n);
                l0r *= sc0; l1r *= sc1;
                m0r = m0n; m1r = m1n;
#pragma unroll
                for (int dt = 0; dt < 16; ++dt) { acc0[dt] *= sc0; acc1[dt] *= sc1; }
            }

            float ps0 = 0.f, ps1 = 0.f;
#pragma unroll
            for (int r = 0; r < 4; ++r) {
                p00[r] = __expf(p00[r] - m0r);
                p10[r] = __expf(p10[r] - m0r);
                p01[r] = __expf(p01[r] - m1r);
                p11[r] = __expf(p11[r] - m1r);
                ps0 += p00[r] + p10[r];
                ps1 += p01[r] + p11[r];
            }
            ps0 += __shfl_xor(ps0, 16); ps0 += __shfl_xor(ps0, 32);
            ps1 += __shfl_xor(ps1, 16); ps1 += __shfl_xor(ps1, 32);
            l0r += ps0; l1r += ps1;

            // P bounce: two per-wave 1KB areas (one per q-block)
            char* pw0 = (char*)&Pls[w][0][0];
            char* pw1 = (char*)&Pls[w][1][0];
#pragma unroll
            for (int t = 0; t < 2; ++t)
#pragma unroll
                for (int u = 0; u < 2; ++u) {
                    const int kk = 16 * t + 4 * g + 2 * u;
                    const int off = c16 * 64 + (((kk >> 3) ^ psw) * 16) + (kk & 7) * 2;
                    const float a0v = t ? p10[2 * u] : p00[2 * u];
                    const float a1v = t ? p10[2 * u + 1] : p00[2 * u + 1];
                    *(uint*)(pw0 + off) = (uint)f2h(a0v) | ((uint)f2h(a1v) << 16);
                    const float b0v = t ? p11[2 * u] : p01[2 * u];
                    const float b1v = t ? p11[2 * u + 1] : p01[2 * u + 1];
                    *(uint*)(pw1 + off) = (uint)f2h(b0v) | ((uint)f2h(b1v) << 16);
                }
            const half8 pfrag0 = *(const half8*)(pw0 + c16 * 64 + ((g ^ psw) * 16));
            const half8 pfrag1 = *(const half8*)(pw1 + c16 * 64 + ((g ^ psw) * 16));

#pragma unroll
            for (int dt = 0; dt < 16; ++dt) {
                const int d = dt * 16 + c16;
                const int phi = ((d >> 1) ^ (d >> 3)) & 3;
                const half8 va = *(const half8*)&Vb[d * 32 + ((g ^ phi) * 8)];
                acc0[dt] = __builtin_amdgcn_mfma_f32_16x16x32_f16(va, pfrag0, acc0[dt], 0, 0, 0);
                acc1[dt] = __builtin_amdgcn_mfma_f32_16x16x32_f16(va, pfrag1, acc1[dt], 0, 0, 0);
            }
        }
        asm volatile("s_waitcnt vmcnt(0)" ::: "memory");
        __syncthreads();
        cur ^= 1;
    }

    // ---- epilogue: ocf[b*SEQ+q][h*256+d] fp16, both q-blocks ----
    const float inv0 = 1.f / l0r;
    const float inv1 = 1.f / l1r;
    ushort* orow0 = ocf + ((size_t)(b * SEQ) + q0) * (HEADS * EMBED) + h * EMBED;
    ushort* orow1 = ocf + ((size_t)(b * SEQ) + q1) * (HEADS * EMBED) + h * EMBED;
#pragma unroll
    for (int dt = 0; dt < 16; ++dt) {
        const f32x4 o0 = acc0[dt] * inv0;
        const f32x4 o1 = acc1[dt] * inv1;
        uint2 P2;
        P2.x = (uint)f2h(o0[0]) | ((uint)f2h(o0[1]) << 16);
        P2.y = (uint)f2h(o0[2]) | ((uint)f2h(o0[3]) << 16);
        *(uint2*)(orow0 + dt * 16 + 4 * g) = P2;
        P2.x = (uint)f2h(o1[0]) | ((uint)f2h(o1[1]) << 16);
        P2.y = (uint)f2h(o1[2]) | ((uint)f2h(o1[3]) << 16);
        *(uint2*)(orow1 + dt * 16 + 4 * g) = P2;
    }
}

extern "C" void kernel_launch(void* const* d_in, const int* in_sizes, int n_in,
                              void* d_out, int out_size, void* d_ws, size_t ws_size,
                              hipStream_t stream) {
    const float* X  = (const float*)d_in[0];
    const float* Wq = (const float*)d_in[1];
    const float* Wk = (const float*)d_in[2];
    const float* Wv = (const float*)d_in[3];
    const float* Wo = (const float*)d_in[4];
    const float* bo = (const float*)d_in[5];

    ushort* ws16 = (ushort*)d_ws;
    ushort* qf   = ws16;                     // [8][8192][256] fp16
    ushort* kf   = ws16 +  8 * QE;           // fp16
    ushort* vtb  = ws16 + 16 * QE;           // [8][256][8192] fp16
    ushort* ocf  = ws16 + 24 * QE;           // [8192][2048] fp16
    ushort* ex   = ws16 + 32 * QE;
    ushort* Xh   = ex;
    ushort* Xl   = ex + 2097152;
    ushort* Wqkh = ex + 2 * 2097152;
    ushort* Wqkl = ex + 3 * 2097152;
    ushort* Wvh  = ex + 4 * 2097152;
    ushort* Wvl  = ex + 4 * 2097152 + 524288;
    ushort* Wof  = ex + 5 * 2097152;
    float*  out  = (float*)d_out;

    split_bf16<<<2048, 256, 0, stream>>>(X, Xh, Xl, 524288);
    split_weights<<<2048, 256, 0, stream>>>(Wq, Wk, Wv, Wo,
                                            Wqkh, Wqkl, Wvh, Wvl, Wof);

    gemm_qk<<<2048, 256, 0, stream>>>(Xh, Xl, Wqkh, Wqkl, qf, kf);
    gemm_vt<<<1024, 256, 0, stream>>>(Wvh, Wvl, Xh, Xl, vtb);

    flash_mfma<<<512, 256, 0, stream>>>(qf, kf, vtb, ocf);

    gemm_out_f16<<<256, 256, 0, stream>>>(ocf, Wof, bo, out);
}